// Round 15
// baseline (138.970 us; speedup 1.0000x reference)
//
#include <hip/hip_runtime.h>

typedef __attribute__((ext_vector_type(8))) short short8;
typedef __attribute__((ext_vector_type(4))) short short4v;
typedef __attribute__((ext_vector_type(4))) float f32x4;
typedef __attribute__((ext_vector_type(16))) float f32x16;
typedef __attribute__((ext_vector_type(2))) unsigned uint2v;
typedef __attribute__((ext_vector_type(4))) unsigned uint4v;

#define T_ 2048
#define H_ 16
#define KVH_ 4
#define QSCALE 0.18033688011112042f   // 0.125 * log2(e): softmax in base-2 domain
#define DEFER 8.0f                    // T13 defer-max threshold (log2 domain)

__device__ inline unsigned short f2bf(float f) {
    unsigned u = __builtin_bit_cast(unsigned, f);
    u += 0x7fff + ((u >> 16) & 1);
    return (unsigned short)(u >> 16);
}
__device__ inline float bf2f(unsigned short v) {
    unsigned u = ((unsigned)v) << 16;
    return __builtin_bit_cast(float, u);
}
__device__ inline unsigned pk2(float lo, float hi) {
    unsigned r;
    asm("v_cvt_pk_bf16_f32 %0, %1, %2" : "=v"(r) : "v"(lo), "v"(hi));
    return r;
}

__device__ inline void gl_lds16(const unsigned short* g, unsigned short* lds) {
    __builtin_amdgcn_global_load_lds(
        (const __attribute__((address_space(1))) unsigned int*)g,
        (__attribute__((address_space(3))) unsigned int*)lds, 16, 0, 0);
}

// ---------------------------------------------------------------------------
// Fused prep: bid <2048: x f32->bf16 cast (8/thread);
//             2048..2303: Wq transpose; 2304..2367: Wk; 2368..2431: Wv;
//             2432..2687: Wo.   W [K][N] f32 -> out [rowoff+N][K] bf16.
// ---------------------------------------------------------------------------
__device__ void tr_tile(const float* __restrict__ W, unsigned short* __restrict__ out,
                        int K, int N, int rowoff, int bx, int by, int tid,
                        unsigned short (*ts)[66]) {
    #pragma unroll
    for (int s = 0; s < 16; ++s) {
        int idx = tid + s * 256;
        int kl = idx >> 6, nl = idx & 63;
        ts[kl][nl] = f2bf(W[(size_t)(by * 64 + kl) * N + bx * 64 + nl]);
    }
    __syncthreads();
    #pragma unroll
    for (int s = 0; s < 16; ++s) {
        int idx = tid + s * 256;
        int nl = idx >> 6, kl = idx & 63;
        out[(size_t)(rowoff + bx * 64 + nl) * K + by * 64 + kl] = ts[kl][nl];
    }
}

__global__ __launch_bounds__(256) void prep_fused(
        const float* __restrict__ x,
        const float* __restrict__ Wq, const float* __restrict__ Wk,
        const float* __restrict__ Wv, const float* __restrict__ Wo,
        unsigned short* __restrict__ xb, unsigned short* __restrict__ Wt,
        unsigned short* __restrict__ Wot) {
    __shared__ unsigned short ts[64][66];
    const int bid = blockIdx.x, tid = threadIdx.x;
    if (bid < 2048) {
        int i = bid * 256 + tid;
        float4 v0 = ((const float4*)x)[i * 2];
        float4 v1 = ((const float4*)x)[i * 2 + 1];
        short8 o;
        o[0] = f2bf(v0.x); o[1] = f2bf(v0.y); o[2] = f2bf(v0.z); o[3] = f2bf(v0.w);
        o[4] = f2bf(v1.x); o[5] = f2bf(v1.y); o[6] = f2bf(v1.z); o[7] = f2bf(v1.w);
        ((short8*)xb)[i] = o;
    } else if (bid < 2304) {
        int t = bid - 2048;
        tr_tile(Wq, Wt, 1024, 1024, 0, t & 15, t >> 4, tid, ts);
    } else if (bid < 2368) {
        int t = bid - 2304;
        tr_tile(Wk, Wt, 1024, 256, 1024, t & 3, t >> 2, tid, ts);
    } else if (bid < 2432) {
        int t = bid - 2368;
        tr_tile(Wv, Wt, 1024, 256, 1280, t & 3, t >> 2, tid, ts);
    } else {
        int t = bid - 2432;
        tr_tile(Wo, Wot, 1024, 1024, 0, t & 15, t >> 4, tid, ts);
    }
}

// ---------------------------------------------------------------------------
// QKV GEMM: 128x128 tile (m97-style: 4 waves 2x2, 64x64/wave, acc 4x4),
// BK=32, gl_lds16 staging.  Fused RoPE/K/V epilogue per 64-col group.
// ---------------------------------------------------------------------------
__global__ __launch_bounds__(256) void gemm_qkv(
        const unsigned short* __restrict__ A,
        const unsigned short* __restrict__ Bt,
        unsigned short* __restrict__ Cq, unsigned short* __restrict__ Ck,
        unsigned short* __restrict__ Cvt,
        const float* __restrict__ rc, const float* __restrict__ rs) {
    const int K = 1024;
    __shared__ __align__(16) unsigned short As[128 * 32];
    __shared__ __align__(16) unsigned short Bs[128 * 32];
    const int tid = threadIdx.x;
    const int w = tid >> 6, l = tid & 63, lk = l & 15, lg = l >> 4;
    const int wr = w >> 1, wc = w & 1;
    const int bx = blockIdx.x, by = blockIdx.y;

    const unsigned short* Arow = A + (size_t)by * 128 * K;
    const unsigned short* Brow = Bt + (size_t)bx * 128 * K;

    f32x4 acc[4][4];
    #pragma unroll
    for (int m = 0; m < 4; ++m)
        #pragma unroll
        for (int n = 0; n < 4; ++n) acc[m][n] = (f32x4){0, 0, 0, 0};

    for (int k0 = 0; k0 < K; k0 += 32) {
        #pragma unroll
        for (int p = 0; p < 2; ++p) {
            int cb = w * 64 + p * 256;
            int c = cb + l;
            int row = c >> 2, ko = (c & 3) * 8;
            gl_lds16(Arow + (size_t)row * K + k0 + ko, As + cb * 8);
            gl_lds16(Brow + (size_t)row * K + k0 + ko, Bs + cb * 8);
        }
        __syncthreads();
        short8 aF[4], bF[4];
        #pragma unroll
        for (int m = 0; m < 4; ++m)
            aF[m] = *(const short8*)&As[(wr * 64 + m * 16 + lk) * 32 + lg * 8];
        #pragma unroll
        for (int n = 0; n < 4; ++n)
            bF[n] = *(const short8*)&Bs[(wc * 64 + n * 16 + lk) * 32 + lg * 8];
        #pragma unroll
        for (int m = 0; m < 4; ++m)
            #pragma unroll
            for (int n = 0; n < 4; ++n)
                acc[m][n] = __builtin_amdgcn_mfma_f32_16x16x32_bf16(
                    aF[m], bF[n], acc[m][n], 0, 0, 0);
        __syncthreads();
    }

    const int rowbase = by * 128 + wr * 64;
    const int colgrp = bx * 2 + wc;
    if (colgrp < 16) {                  // ---- Q: RoPE * QSCALE
        const int h = colgrp;
        #pragma unroll
        for (int m = 0; m < 4; ++m)
            #pragma unroll
            for (int r = 0; r < 4; ++r) {
                int trow = rowbase + m * 16 + lg * 4 + r;
                int b = trow >> 11, t = trow & (T_ - 1);
                size_t ob = (((size_t)(b * 16 + h)) * T_ + t) * 64;
                #pragma unroll
                for (int n = 0; n < 2; ++n) {
                    int d = n * 16 + lk;
                    float cc = rc[t * 32 + d], ss = rs[t * 32 + d];
                    float x1 = acc[m][n][r], x2 = acc[m][n + 2][r];
                    Cq[ob + d]      = f2bf((x1 * cc - x2 * ss) * QSCALE);
                    Cq[ob + d + 32] = f2bf((x2 * cc + x1 * ss) * QSCALE);
                }
            }
    } else if (colgrp < 20) {           // ---- K: RoPE
        const int kvh = colgrp - 16;
        #pragma unroll
        for (int m = 0; m < 4; ++m)
            #pragma unroll
            for (int r = 0; r < 4; ++r) {
                int trow = rowbase + m * 16 + lg * 4 + r;
                int b = trow >> 11, t = trow & (T_ - 1);
                size_t ob = (((size_t)(b * 4 + kvh)) * T_ + t) * 64;
                #pragma unroll
                for (int n = 0; n < 2; ++n) {
                    int d = n * 16 + lk;
                    float cc = rc[t * 32 + d], ss = rs[t * 32 + d];
                    float x1 = acc[m][n][r], x2 = acc[m][n + 2][r];
                    Ck[ob + d]      = f2bf(x1 * cc - x2 * ss);
                    Ck[ob + d + 32] = f2bf(x2 * cc + x1 * ss);
                }
            }
    } else {                            // ---- V -> [B][4][64][T]
        const int kvh = colgrp - 20;
        #pragma unroll
        for (int m = 0; m < 4; ++m) {
            int trow0 = rowbase + m * 16 + lg * 4;
            int b = trow0 >> 11, t0 = trow0 & (T_ - 1);
            #pragma unroll
            for (int n = 0; n < 4; ++n) {
                int d = n * 16 + lk;
                short4v pk;
                #pragma unroll
                for (int r = 0; r < 4; ++r) pk[r] = f2bf(acc[m][n][r]);
                *(short4v*)(Cvt + (((size_t)(b * 4 + kvh)) * 64 + d) * T_ + t0) = pk;
            }
        }
    }
}

// ---------------------------------------------------------------------------
// O-projection GEMM: 128x64 tile, BK=32, gl_lds16 staging.  C = f32 [M][N].
// ---------------------------------------------------------------------------
__global__ __launch_bounds__(256) void gemm_o(
        const unsigned short* __restrict__ A,
        const unsigned short* __restrict__ Bt,
        float* __restrict__ C, int M, int N, int K) {
    __shared__ __align__(16) unsigned short As[128 * 32];
    __shared__ __align__(16) unsigned short Bs[64 * 32];
    const int tid = threadIdx.x;
    const int w = tid >> 6, l = tid & 63, lk = l & 15, lg = l >> 4;
    const int bx = blockIdx.x, by = blockIdx.y;

    const unsigned short* Arow = A + (size_t)by * 128 * K;
    const unsigned short* Brow = Bt + (size_t)bx * 64 * K;

    f32x4 acc[2][4];
    #pragma unroll
    for (int m = 0; m < 2; ++m)
        #pragma unroll
        for (int n = 0; n < 4; ++n) acc[m][n] = (f32x4){0, 0, 0, 0};

    for (int k0 = 0; k0 < K; k0 += 32) {
        #pragma unroll
        for (int p = 0; p < 2; ++p) {
            int cb = p * 256 + w * 64;
            int c = cb + l;
            int row = c >> 2, ko = (c & 3) * 8;
            gl_lds16(Arow + (size_t)row * K + k0 + ko, As + cb * 8);
        }
        {
            int c = w * 64 + l;
            int row = c >> 2, ko = (c & 3) * 8;
            gl_lds16(Brow + (size_t)row * K + k0 + ko, Bs + c * 8);
        }
        __syncthreads();
        short8 aF[2], bF[4];
        #pragma unroll
        for (int m = 0; m < 2; ++m)
            aF[m] = *(const short8*)&As[(w * 32 + m * 16 + lk) * 32 + lg * 8];
        #pragma unroll
        for (int n = 0; n < 4; ++n)
            bF[n] = *(const short8*)&Bs[(n * 16 + lk) * 32 + lg * 8];
        #pragma unroll
        for (int m = 0; m < 2; ++m)
            #pragma unroll
            for (int n = 0; n < 4; ++n)
                acc[m][n] = __builtin_amdgcn_mfma_f32_16x16x32_bf16(
                    aF[m], bF[n], acc[m][n], 0, 0, 0);
        __syncthreads();
    }

    const int rowbase = by * 128 + w * 32;
    #pragma unroll
    for (int m = 0; m < 2; ++m)
        #pragma unroll
        for (int r = 0; r < 4; ++r) {
            size_t ro = (size_t)(rowbase + m * 16 + lg * 4 + r) * N + bx * 64 + lk;
            #pragma unroll
            for (int n = 0; n < 4; ++n) C[ro + n * 16] = acc[m][n][r];
        }
}

// ---------------------------------------------------------------------------
// Flash attention v11: NO LDS, NO BARRIERS. K/V are L2/L1-resident (512 KB per
// (b,kv)); each wave loads its MFMA fragments straight to registers.
// Swapped QK^T (S^T = K*Q, mfma_32x32x16), in-register softmax, cvt_pk +
// permlane32_swap P redistribution. V loads issued before softmax (T14: the
// softmax covers their L2 latency). kf/vf lifetimes disjoint -> regs shared.
// Split-K mapping r10 (empirical best), combine unchanged.
// ---------------------------------------------------------------------------
#define CROW(r, hi) (((r) & 3) + 8 * ((r) >> 2) + 4 * (hi))

__global__ __launch_bounds__(256) void attn_mfma(
        const unsigned short* __restrict__ Q,   // [B][16][T][64] (pre-scaled, log2 domain)
        const unsigned short* __restrict__ K,   // [B][4][T][64]
        const unsigned short* __restrict__ Vt,  // [B][4][64][T]
        unsigned short* __restrict__ O,         // [B*T][16][64] bf16
        float* __restrict__ PM, float* __restrict__ PLp,
        unsigned short* __restrict__ PACC) {
    const int bid = blockIdx.x;
    int bh, qt, kt0, ktend, ck;
    bool direct;
    if (bid < 256) {
        bh = bid & 31; qt = 8 + (bid >> 5);
        kt0 = 0; ktend = 16; ck = 0; direct = false;
    } else if (bid < 512) {
        int j = bid - 256;
        bh = j & 31; qt = 7 - (j >> 5);
        kt0 = 0; ktend = 2 * qt + 2; ck = 0; direct = true;
    } else {
        int j = bid - 512;
        bh = j & 31; qt = 15 - (j >> 5);     // r10 mapping (empirical best)
        kt0 = 16; ktend = 2 * qt + 2; ck = 1; direct = false;
    }
    const int nkt = ktend - kt0;
    const int h = bh & 15, b = bh >> 4, kv = h >> 2;
    const int tid = threadIdx.x;
    const int w = tid >> 6, l = tid & 63;
    const int q32 = l & 31, hi = l >> 5;

    const unsigned short* Kb = K + ((size_t)(b * 4 + kv)) * T_ * 64;
    const unsigned short* Vb = Vt + ((size_t)(b * 4 + kv)) * 64 * T_;
    // per-lane fragment bases
    const unsigned short* Kf0 = Kb + (size_t)q32 * 64 + hi * 8;         // +kt*4096, +16s
    const unsigned short* Kf1 = Kb + (size_t)(32 + q32) * 64 + hi * 8;
    const unsigned short* Vf0 = Vb + (size_t)q32 * T_ + hi * 8;         // +kt*64, +16ks
    const unsigned short* Vf1 = Vb + (size_t)(32 + q32) * T_ + hi * 8;

    // Q B-frags: lane holds q=l&31, d=16s+hi*8+j
    short8 qf[4];
    {
        const unsigned short* qp =
            Q + (((size_t)(b * 16 + h)) * T_ + qt * 128 + w * 32 + q32) * 64 + hi * 8;
        #pragma unroll
        for (int s = 0; s < 4; ++s) qf[s] = *(const short8*)(qp + 16 * s);
    }

    f32x16 o0, o1;                // O^T: col d = dt*32+q32, rows q = crow(r,hi)
    #pragma unroll
    for (int i = 0; i < 16; ++i) { o0[i] = 0.f; o1[i] = 0.f; }
    float mloc = -1e38f, lsum = 0.f;

    // build PV A-frag word group from 8 P values (post-exp2, q=lane-local)
    auto mk = [&](float e0, float e1, float e2, float e3,
                  float e4, float e5, float e6, float e7) -> short8 {
        unsigned a0 = pk2(e0, e1);
        unsigned b0 = pk2(e4, e5);
        uint2v r02 = __builtin_amdgcn_permlane32_swap(a0, b0, false, false);
        unsigned a1 = pk2(e2, e3);
        unsigned b1 = pk2(e6, e7);
        uint2v r13 = __builtin_amdgcn_permlane32_swap(a1, b1, false, false);
        uint4v u;
        u[0] = r02[0]; u[1] = r13[0]; u[2] = r02[1]; u[3] = r13[1];
        return __builtin_bit_cast(short8, u);
    };

    for (int i = 0; i < nkt; ++i) {
        const int kt = kt0 + i;

        // ---- K fragments: global -> regs (L1/L2-resident)
        short8 kf0[4], kf1[4];
        #pragma unroll
        for (int s = 0; s < 4; ++s) {
            kf0[s] = *(const short8*)(Kf0 + (size_t)kt * 4096 + 16 * s);
            kf1[s] = *(const short8*)(Kf1 + (size_t)kt * 4096 + 16 * s);
        }

        // ---- S^T = K Q
        f32x16 st0, st1;
        #pragma unroll
        for (int r = 0; r < 16; ++r) { st0[r] = 0.f; st1[r] = 0.f; }
        __builtin_amdgcn_s_setprio(1);
        #pragma unroll
        for (int s = 0; s < 4; ++s) {
            st0 = __builtin_amdgcn_mfma_f32_32x32x16_bf16(kf0[s], qf[s], st0, 0, 0, 0);
            st1 = __builtin_amdgcn_mfma_f32_32x32x16_bf16(kf1[s], qf[s], st1, 0, 0, 0);
        }
        __builtin_amdgcn_s_setprio(0);

        // ---- V fragments issued NOW; softmax below covers their latency
        short8 vf0[4], vf1[4];
        #pragma unroll
        for (int ks = 0; ks < 4; ++ks) {
            vf0[ks] = *(const short8*)(Vf0 + kt * 64 + 16 * ks);
            vf1[ks] = *(const short8*)(Vf1 + kt * 64 + 16 * ks);
        }

        if (kt >= 2 * qt) {                    // diagonal region mask
            const int qg = qt * 128 + w * 32 + q32;
            #pragma unroll
            for (int r = 0; r < 16; ++r) {
                const int kg = kt * 64 + CROW(r, hi);
                if (kg > qg)      st0[r] = -1e30f;
                if (kg + 32 > qg) st1[r] = -1e30f;
            }
        }

        // ---- row max: pairwise tree (depth 5) + one cross-half exchange
        float tm[16];
        #pragma unroll
        for (int r = 0; r < 16; ++r) tm[r] = fmaxf(st0[r], st1[r]);
        #pragma unroll
        for (int d = 8; d >= 1; d >>= 1)
            #pragma unroll
            for (int r = 0; r < d; ++r) tm[r] = fmaxf(tm[r], tm[r + d]);
        float pm = fmaxf(tm[0], __shfl_xor(tm[0], 32));

        // ---- defer-max rescale (rare)
        if (__any(pm > mloc + DEFER)) {
            const float nm = fmaxf(mloc, pm);
            const float corr = exp2f(mloc - nm);
            mloc = nm;
            lsum *= corr;
            #pragma unroll
            for (int r = 0; r < 16; ++r) {
                const float cr = __shfl(corr, CROW(r, hi));
                o0[r] *= cr;
                o1[r] *= cr;
            }
        }

        // ---- exp2 + tree sum
        float ts[16];
        #pragma unroll
        for (int r = 0; r < 16; ++r) {
            st0[r] = exp2f(st0[r] - mloc);
            st1[r] = exp2f(st1[r] - mloc);
            ts[r] = st0[r] + st1[r];
        }
        #pragma unroll
        for (int d = 8; d >= 1; d >>= 1)
            #pragma unroll
            for (int r = 0; r < d; ++r) ts[r] += ts[r + d];
        lsum += ts[0] + __shfl_xor(ts[0], 32);

        // ---- P -> PV A-frags (16 cvt_pk + 8 permlane32_swap)
        short8 pa0 = mk(st0[0], st0[1], st0[2],  st0[3],  st0[4],  st0[5],  st0[6],  st0[7]);
        short8 pa1 = mk(st0[8], st0[9], st0[10], st0[11], st0[12], st0[13], st0[14], st0[15]);
        short8 pa2 = mk(st1[0], st1[1], st1[2],  st1[3],  st1[4],  st1[5],  st1[6],  st1[7]);
        short8 pa3 = mk(st1[8], st1[9], st1[10], st1[11], st1[12], st1[13], st1[14], st1[15]);

        // ---- O^T += P V
        __builtin_amdgcn_s_setprio(1);
        #pragma unroll
        for (int ks = 0; ks < 4; ++ks) {
            short8 paf = (ks == 0) ? pa0 : (ks == 1) ? pa1 : (ks == 2) ? pa2 : pa3;
            o0 = __builtin_amdgcn_mfma_f32_32x32x16_bf16(paf, vf0[ks], o0, 0, 0, 0);
            o1 = __builtin_amdgcn_mfma_f32_32x32x16_bf16(paf, vf1[ks], o1, 0, 0, 0);
        }
        __builtin_amdgcn_s_setprio(0);
    }

    if (direct) {
        #pragma unroll
        for (int r = 0; r < 16; ++r) {
            const float inv = 1.f / __shfl(lsum, CROW(r, hi));
            const int t = qt * 128 + w * 32 + CROW(r, hi);
            unsigned short* op = &O[(((size_t)(b * T_ + t)) * 16 + h) * 64 + q32];
            op[0]  = f2bf(o0[r] * inv);
            op[32] = f2bf(o1[r] * inv);
        }
    } else {
        const int p = ((bh << 3) + (qt - 8)) * 2 + ck;
        if (l < 32) {
            PM[p * 128 + w * 32 + l]  = mloc;
            PLp[p * 128 + w * 32 + l] = lsum;
        }
        #pragma unroll
        for (int r = 0; r < 16; ++r) {
            const int row = w * 32 + CROW(r, hi);
            unsigned short* pp = &PACC[((size_t)p * 128 + row) * 64 + q32];
            pp[0]  = f2bf(o0[r]);
            pp[32] = f2bf(o1[r]);
        }
    }
}

// ---------------------------------------------------------------------------
// Combine two split-K partials per (b,h,long-qt).  256 blocks x 256 threads.
// ---------------------------------------------------------------------------
__global__ __launch_bounds__(256) void combine_attn(
        const float* __restrict__ PM, const float* __restrict__ PLp,
        const unsigned short* __restrict__ PACC,
        unsigned short* __restrict__ O) {
    const int cid = blockIdx.x;
    const int bh = cid & 31, qt = 8 + (cid >> 5);
    const int h = bh & 15, b = bh >> 4;
    const int tid = threadIdx.x;
    const int row = tid >> 1, cg = (tid & 1) * 32;
    const int p0 = ((bh << 3) + (qt - 8)) * 2, p1 = p0 + 1;

    float mA = PM[p0 * 128 + row], mB = PM[p1 * 128 + row];
    float lA = PLp[p0 * 128 + row], lB = PLp[p1 * 128 + row];
    float M = fmaxf(mA, mB);
    float wA = exp2f(mA - M), wB = exp2f(mB - M);
    float inv = 1.f / (lA * wA + lB * wB);
    wA *= inv; wB *= inv;

    const unsigned short* a = &PACC[((size_t)p0 * 128 + row) * 64 + cg];
    const unsigned short* c = &PACC[((size_t)p1 * 128 + row) * 64 + cg];
    int t = qt * 128 + row;
    unsigned short* op = &O[(((size_t)(b * T_ + t)) * 16 + h) * 64 + cg];
    #pragma unroll
    for (int j = 0; j < 4; ++j) {
        short8 va = *(const short8*)(a + j * 8);
        short8 vb = *(const short8*)(c + j * 8);
        short8 o;
        #pragma unroll
        for (int i = 0; i < 8; ++i)
            o[i] = f2bf(bf2f((unsigned short)va[i]) * wA +
                        bf2f((unsigned short)vb[i]) * wB);
        *(short8*)(op + j * 8) = o;
    }
}

// ---------------------------------------------------------------------------
extern "C" void kernel_launch(void* const* d_in, const int* in_sizes, int n_in,
                              void* d_out, int out_size, void* d_ws, size_t ws_size,
                              hipStream_t stream) {
    const float* x  = (const float*)d_in[0];
    const float* rc = (const float*)d_in[1];
    const float* rs = (const float*)d_in[2];
    const float* Wq = (const float*)d_in[4];
    const float* Wk = (const float*)d_in[5];
    const float* Wv = (const float*)d_in[6];
    const float* Wo = (const float*)d_in[7];
    float* out = (float*)d_out;

    unsigned short* ws = (unsigned short*)d_ws;
    unsigned short* xb  = ws;                        // 4M shorts (dead after QKV)
    unsigned short* Wt  = ws + 4194304;              // 1.5M (dead after QKV)
    unsigned short* Wot = ws + 5767168;              // 1M
    unsigned short* Qbf = ws + 6815744;              // 4M
    unsigned short* Kbf = ws + 11010048;             // 1M
    unsigned short* Vtb = ws + 12058624;             // 1M
    unsigned short* Ob  = ws + 13107200;             // 4M

    // split-K partials reuse the dead xb/Wt region
    float* PM            = (float*)d_ws;                         // [512][128] f32
    float* PLp           = PM + 512 * 128;                       // [512][128] f32
    unsigned short* PACC = (unsigned short*)(PLp + 512 * 128);   // [512][128][64] bf16

    dim3 blk(256);
    prep_fused<<<dim3(2688), blk, 0, stream>>>(x, Wq, Wk, Wv, Wo, xb, Wt, Wot);

    gemm_qkv<<<dim3(12, 32), blk, 0, stream>>>(xb, Wt, Qbf, Kbf, Vtb, rc, rs);

    attn_mfma<<<dim3(768), blk, 0, stream>>>(Qbf, Kbf, Vtb, Ob, PM, PLp, PACC);
    combine_attn<<<dim3(256), blk, 0, stream>>>(PM, PLp, PACC, Ob);

    gemm_o<<<dim3(16, 32), blk, 0, stream>>>(Ob, Wot, out, 4096, 1024, 1024);
}

// Round 16
// 113.625 us; speedup vs baseline: 1.2231x; 1.2231x over previous
//
#include <hip/hip_runtime.h>

typedef __attribute__((ext_vector_type(8))) short short8;
typedef __attribute__((ext_vector_type(4))) short short4v;
typedef __attribute__((ext_vector_type(4))) float f32x4;
typedef __attribute__((ext_vector_type(16))) float f32x16;
typedef __attribute__((ext_vector_type(2))) unsigned uint2v;
typedef __attribute__((ext_vector_type(4))) unsigned uint4v;

#define T_ 2048
#define H_ 16
#define KVH_ 4
#define QSCALE 0.18033688011112042f   // 0.125 * log2(e): softmax in base-2 domain
#define DEFER 8.0f                    // T13 defer-max threshold (log2 domain)

__device__ inline unsigned short f2bf(float f) {
    unsigned u = __builtin_bit_cast(unsigned, f);
    u += 0x7fff + ((u >> 16) & 1);
    return (unsigned short)(u >> 16);
}
__device__ inline float bf2f(unsigned short v) {
    unsigned u = ((unsigned)v) << 16;
    return __builtin_bit_cast(float, u);
}
__device__ inline unsigned pk2(float lo, float hi) {
    unsigned r;
    asm("v_cvt_pk_bf16_f32 %0, %1, %2" : "=v"(r) : "v"(lo), "v"(hi));
    return r;
}

__device__ inline void gl_lds16(const unsigned short* g, unsigned short* lds) {
    __builtin_amdgcn_global_load_lds(
        (const __attribute__((address_space(1))) unsigned int*)g,
        (__attribute__((address_space(3))) unsigned int*)lds, 16, 0, 0);
}

// ---------------------------------------------------------------------------
// Fused prep: bid <2048: x f32->bf16 cast (8/thread);
//             2048..2303: Wq transpose; 2304..2367: Wk; 2368..2431: Wv;
//             2432..2687: Wo.   W [K][N] f32 -> out [rowoff+N][K] bf16.
// ---------------------------------------------------------------------------
__device__ void tr_tile(const float* __restrict__ W, unsigned short* __restrict__ out,
                        int K, int N, int rowoff, int bx, int by, int tid,
                        unsigned short (*ts)[66]) {
    #pragma unroll
    for (int s = 0; s < 16; ++s) {
        int idx = tid + s * 256;
        int kl = idx >> 6, nl = idx & 63;
        ts[kl][nl] = f2bf(W[(size_t)(by * 64 + kl) * N + bx * 64 + nl]);
    }
    __syncthreads();
    #pragma unroll
    for (int s = 0; s < 16; ++s) {
        int idx = tid + s * 256;
        int nl = idx >> 6, kl = idx & 63;
        out[(size_t)(rowoff + bx * 64 + nl) * K + by * 64 + kl] = ts[kl][nl];
    }
}

__global__ __launch_bounds__(256) void prep_fused(
        const float* __restrict__ x,
        const float* __restrict__ Wq, const float* __restrict__ Wk,
        const float* __restrict__ Wv, const float* __restrict__ Wo,
        unsigned short* __restrict__ xb, unsigned short* __restrict__ Wt,
        unsigned short* __restrict__ Wot) {
    __shared__ unsigned short ts[64][66];
    const int bid = blockIdx.x, tid = threadIdx.x;
    if (bid < 2048) {
        int i = bid * 256 + tid;
        float4 v0 = ((const float4*)x)[i * 2];
        float4 v1 = ((const float4*)x)[i * 2 + 1];
        short8 o;
        o[0] = f2bf(v0.x); o[1] = f2bf(v0.y); o[2] = f2bf(v0.z); o[3] = f2bf(v0.w);
        o[4] = f2bf(v1.x); o[5] = f2bf(v1.y); o[6] = f2bf(v1.z); o[7] = f2bf(v1.w);
        ((short8*)xb)[i] = o;
    } else if (bid < 2304) {
        int t = bid - 2048;
        tr_tile(Wq, Wt, 1024, 1024, 0, t & 15, t >> 4, tid, ts);
    } else if (bid < 2368) {
        int t = bid - 2304;
        tr_tile(Wk, Wt, 1024, 256, 1024, t & 3, t >> 2, tid, ts);
    } else if (bid < 2432) {
        int t = bid - 2368;
        tr_tile(Wv, Wt, 1024, 256, 1280, t & 3, t >> 2, tid, ts);
    } else {
        int t = bid - 2432;
        tr_tile(Wo, Wot, 1024, 1024, 0, t & 15, t >> 4, tid, ts);
    }
}

// ---------------------------------------------------------------------------
// QKV GEMM: 128x128 tile (m97-style: 4 waves 2x2, 64x64/wave, acc 4x4),
// BK=32, gl_lds16 staging.  Fused RoPE/K/V epilogue per 64-col group.
// ---------------------------------------------------------------------------
__global__ __launch_bounds__(256) void gemm_qkv(
        const unsigned short* __restrict__ A,
        const unsigned short* __restrict__ Bt,
        unsigned short* __restrict__ Cq, unsigned short* __restrict__ Ck,
        unsigned short* __restrict__ Cvt,
        const float* __restrict__ rc, const float* __restrict__ rs) {
    const int K = 1024;
    __shared__ __align__(16) unsigned short As[128 * 32];
    __shared__ __align__(16) unsigned short Bs[128 * 32];
    const int tid = threadIdx.x;
    const int w = tid >> 6, l = tid & 63, lk = l & 15, lg = l >> 4;
    const int wr = w >> 1, wc = w & 1;
    const int bx = blockIdx.x, by = blockIdx.y;

    const unsigned short* Arow = A + (size_t)by * 128 * K;
    const unsigned short* Brow = Bt + (size_t)bx * 128 * K;

    f32x4 acc[4][4];
    #pragma unroll
    for (int m = 0; m < 4; ++m)
        #pragma unroll
        for (int n = 0; n < 4; ++n) acc[m][n] = (f32x4){0, 0, 0, 0};

    for (int k0 = 0; k0 < K; k0 += 32) {
        #pragma unroll
        for (int p = 0; p < 2; ++p) {
            int cb = w * 64 + p * 256;
            int c = cb + l;
            int row = c >> 2, ko = (c & 3) * 8;
            gl_lds16(Arow + (size_t)row * K + k0 + ko, As + cb * 8);
            gl_lds16(Brow + (size_t)row * K + k0 + ko, Bs + cb * 8);
        }
        __syncthreads();
        short8 aF[4], bF[4];
        #pragma unroll
        for (int m = 0; m < 4; ++m)
            aF[m] = *(const short8*)&As[(wr * 64 + m * 16 + lk) * 32 + lg * 8];
        #pragma unroll
        for (int n = 0; n < 4; ++n)
            bF[n] = *(const short8*)&Bs[(wc * 64 + n * 16 + lk) * 32 + lg * 8];
        #pragma unroll
        for (int m = 0; m < 4; ++m)
            #pragma unroll
            for (int n = 0; n < 4; ++n)
                acc[m][n] = __builtin_amdgcn_mfma_f32_16x16x32_bf16(
                    aF[m], bF[n], acc[m][n], 0, 0, 0);
        __syncthreads();
    }

    const int rowbase = by * 128 + wr * 64;
    const int colgrp = bx * 2 + wc;
    if (colgrp < 16) {                  // ---- Q: RoPE * QSCALE
        const int h = colgrp;
        #pragma unroll
        for (int m = 0; m < 4; ++m)
            #pragma unroll
            for (int r = 0; r < 4; ++r) {
                int trow = rowbase + m * 16 + lg * 4 + r;
                int b = trow >> 11, t = trow & (T_ - 1);
                size_t ob = (((size_t)(b * 16 + h)) * T_ + t) * 64;
                #pragma unroll
                for (int n = 0; n < 2; ++n) {
                    int d = n * 16 + lk;
                    float cc = rc[t * 32 + d], ss = rs[t * 32 + d];
                    float x1 = acc[m][n][r], x2 = acc[m][n + 2][r];
                    Cq[ob + d]      = f2bf((x1 * cc - x2 * ss) * QSCALE);
                    Cq[ob + d + 32] = f2bf((x2 * cc + x1 * ss) * QSCALE);
                }
            }
    } else if (colgrp < 20) {           // ---- K: RoPE
        const int kvh = colgrp - 16;
        #pragma unroll
        for (int m = 0; m < 4; ++m)
            #pragma unroll
            for (int r = 0; r < 4; ++r) {
                int trow = rowbase + m * 16 + lg * 4 + r;
                int b = trow >> 11, t = trow & (T_ - 1);
                size_t ob = (((size_t)(b * 4 + kvh)) * T_ + t) * 64;
                #pragma unroll
                for (int n = 0; n < 2; ++n) {
                    int d = n * 16 + lk;
                    float cc = rc[t * 32 + d], ss = rs[t * 32 + d];
                    float x1 = acc[m][n][r], x2 = acc[m][n + 2][r];
                    Ck[ob + d]      = f2bf(x1 * cc - x2 * ss);
                    Ck[ob + d + 32] = f2bf(x2 * cc + x1 * ss);
                }
            }
    } else {                            // ---- V -> [B][4][64][T]
        const int kvh = colgrp - 20;
        #pragma unroll
        for (int m = 0; m < 4; ++m) {
            int trow0 = rowbase + m * 16 + lg * 4;
            int b = trow0 >> 11, t0 = trow0 & (T_ - 1);
            #pragma unroll
            for (int n = 0; n < 4; ++n) {
                int d = n * 16 + lk;
                short4v pk;
                #pragma unroll
                for (int r = 0; r < 4; ++r) pk[r] = f2bf(acc[m][n][r]);
                *(short4v*)(Cvt + (((size_t)(b * 4 + kvh)) * 64 + d) * T_ + t0) = pk;
            }
        }
    }
}

// ---------------------------------------------------------------------------
// O-projection GEMM: 128x64 tile, BK=32, gl_lds16 staging.  C = f32 [M][N].
// ---------------------------------------------------------------------------
__global__ __launch_bounds__(256) void gemm_o(
        const unsigned short* __restrict__ A,
        const unsigned short* __restrict__ Bt,
        float* __restrict__ C, int M, int N, int K) {
    __shared__ __align__(16) unsigned short As[128 * 32];
    __shared__ __align__(16) unsigned short Bs[64 * 32];
    const int tid = threadIdx.x;
    const int w = tid >> 6, l = tid & 63, lk = l & 15, lg = l >> 4;
    const int bx = blockIdx.x, by = blockIdx.y;

    const unsigned short* Arow = A + (size_t)by * 128 * K;
    const unsigned short* Brow = Bt + (size_t)bx * 64 * K;

    f32x4 acc[2][4];
    #pragma unroll
    for (int m = 0; m < 2; ++m)
        #pragma unroll
        for (int n = 0; n < 4; ++n) acc[m][n] = (f32x4){0, 0, 0, 0};

    for (int k0 = 0; k0 < K; k0 += 32) {
        #pragma unroll
        for (int p = 0; p < 2; ++p) {
            int cb = p * 256 + w * 64;
            int c = cb + l;
            int row = c >> 2, ko = (c & 3) * 8;
            gl_lds16(Arow + (size_t)row * K + k0 + ko, As + cb * 8);
        }
        {
            int c = w * 64 + l;
            int row = c >> 2, ko = (c & 3) * 8;
            gl_lds16(Brow + (size_t)row * K + k0 + ko, Bs + c * 8);
        }
        __syncthreads();
        short8 aF[2], bF[4];
        #pragma unroll
        for (int m = 0; m < 2; ++m)
            aF[m] = *(const short8*)&As[(w * 32 + m * 16 + lk) * 32 + lg * 8];
        #pragma unroll
        for (int n = 0; n < 4; ++n)
            bF[n] = *(const short8*)&Bs[(n * 16 + lk) * 32 + lg * 8];
        #pragma unroll
        for (int m = 0; m < 2; ++m)
            #pragma unroll
            for (int n = 0; n < 4; ++n)
                acc[m][n] = __builtin_amdgcn_mfma_f32_16x16x32_bf16(
                    aF[m], bF[n], acc[m][n], 0, 0, 0);
        __syncthreads();
    }

    const int rowbase = by * 128 + w * 32;
    #pragma unroll
    for (int m = 0; m < 2; ++m)
        #pragma unroll
        for (int r = 0; r < 4; ++r) {
            size_t ro = (size_t)(rowbase + m * 16 + lg * 4 + r) * N + bx * 64 + lk;
            #pragma unroll
            for (int n = 0; n < 4; ++n) C[ro + n * 16] = acc[m][n][r];
        }
}

// ---------------------------------------------------------------------------
// Flash attention v12 = r14 (LDS staging, proven 54us) + lsum via ones-MFMA:
// row-sum tree (VALU) replaced by 4 MFMAs/iter on the idle matrix pipe;
// lv[r] lands in o0[r]'s row layout -> epilogue shfl removed too.
// Swapped QK^T, in-register softmax, cvt_pk + permlane32_swap, XOR-swizzled
// LDS, tree max-reduce, r10 split-K mapping.
// ---------------------------------------------------------------------------
#define SWC(row, col) ((col) ^ (((row) & 7) << 3))
#define CROW(r, hi) (((r) & 3) + 8 * ((r) >> 2) + 4 * (hi))

__global__ __launch_bounds__(256) void attn_mfma(
        const unsigned short* __restrict__ Q,   // [B][16][T][64] (pre-scaled, log2 domain)
        const unsigned short* __restrict__ K,   // [B][4][T][64]
        const unsigned short* __restrict__ Vt,  // [B][4][64][T]
        unsigned short* __restrict__ O,         // [B*T][16][64] bf16
        float* __restrict__ PM, float* __restrict__ PLp,
        unsigned short* __restrict__ PACC) {
    __shared__ __align__(16) unsigned short Ks[2][64 * 64];
    __shared__ __align__(16) unsigned short Vs[2][64 * 64];

    const int bid = blockIdx.x;
    int bh, qt, kt0, ktend, ck;
    bool direct;
    if (bid < 256) {
        bh = bid & 31; qt = 8 + (bid >> 5);
        kt0 = 0; ktend = 16; ck = 0; direct = false;
    } else if (bid < 512) {
        int j = bid - 256;
        bh = j & 31; qt = 7 - (j >> 5);
        kt0 = 0; ktend = 2 * qt + 2; ck = 0; direct = true;
    } else {
        int j = bid - 512;
        bh = j & 31; qt = 15 - (j >> 5);     // r10 mapping (empirical best)
        kt0 = 16; ktend = 2 * qt + 2; ck = 1; direct = false;
    }
    const int nkt = ktend - kt0;
    const int h = bh & 15, b = bh >> 4, kv = h >> 2;
    const int tid = threadIdx.x;
    const int w = tid >> 6, l = tid & 63;
    const int q32 = l & 31, hi = l >> 5;

    const unsigned short* Kb = K + ((size_t)(b * 4 + kv)) * T_ * 64;
    const unsigned short* Vb = Vt + ((size_t)(b * 4 + kv)) * 64 * T_;

    // Q B-frags: lane holds q=l&31, d=16s+hi*8+j
    short8 qf[4];
    {
        const unsigned short* qp =
            Q + (((size_t)(b * 16 + h)) * T_ + qt * 128 + w * 32 + q32) * 64 + hi * 8;
        #pragma unroll
        for (int s = 0; s < 4; ++s) qf[s] = *(const short8*)(qp + 16 * s);
    }

    f32x16 o0, o1, lv;            // O^T halves + row-sum accumulator (ones-MFMA)
    #pragma unroll
    for (int i = 0; i < 16; ++i) { o0[i] = 0.f; o1[i] = 0.f; lv[i] = 0.f; }
    float mloc = -1e38f;

    short8 ones;
    #pragma unroll
    for (int i = 0; i < 8; ++i) ones[i] = (short)0x3F80;   // bf16 1.0

    // staging: linear LDS dest, pre-swizzled global source (m173 pattern)
    const int sr = l >> 3, sg = l & 7;
    auto stage = [&](int buf, int kt) {
        #pragma unroll
        for (int p = 0; p < 2; ++p) {
            const int ch = w * 2 + p;
            const int row = ch * 8 + sr;
            const int gs = (sg ^ sr) * 8;
            gl_lds16(Kb + ((size_t)(kt * 64 + row)) * 64 + gs, &Ks[buf][ch * 512]);
            gl_lds16(Vb + (size_t)row * T_ + kt * 64 + gs,     &Vs[buf][ch * 512]);
        }
    };

    // build PV A-frag word group from 8 P values (post-exp2, q=lane-local)
    auto mk = [&](float e0, float e1, float e2, float e3,
                  float e4, float e5, float e6, float e7) -> short8 {
        unsigned a0 = pk2(e0, e1);
        unsigned b0 = pk2(e4, e5);
        uint2v r02 = __builtin_amdgcn_permlane32_swap(a0, b0, false, false);
        unsigned a1 = pk2(e2, e3);
        unsigned b1 = pk2(e6, e7);
        uint2v r13 = __builtin_amdgcn_permlane32_swap(a1, b1, false, false);
        uint4v u;
        u[0] = r02[0]; u[1] = r13[0]; u[2] = r02[1]; u[3] = r13[1];
        return __builtin_bit_cast(short8, u);
    };

    stage(0, kt0);
    for (int i = 0; i < nkt; ++i) {
        const int kt = kt0 + i;
        const int cur = i & 1;
        __syncthreads();                       // DMA drained: buf[cur] ready
        if (i + 1 < nkt) stage(cur ^ 1, kt0 + i + 1);

        // ---- S^T = K Q  (A=K rows k, B=Q cols q); two 32-k subtiles
        f32x16 st0, st1;
        #pragma unroll
        for (int r = 0; r < 16; ++r) { st0[r] = 0.f; st1[r] = 0.f; }
        __builtin_amdgcn_s_setprio(1);
        #pragma unroll
        for (int s = 0; s < 4; ++s) {
            const int c = 16 * s + hi * 8;
            const int kr0 = q32, kr1 = 32 + q32;
            short8 k0 = *(const short8*)&Ks[cur][kr0 * 64 + SWC(kr0, c)];
            short8 k1 = *(const short8*)&Ks[cur][kr1 * 64 + SWC(kr1, c)];
            st0 = __builtin_amdgcn_mfma_f32_32x32x16_bf16(k0, qf[s], st0, 0, 0, 0);
            st1 = __builtin_amdgcn_mfma_f32_32x32x16_bf16(k1, qf[s], st1, 0, 0, 0);
        }
        __builtin_amdgcn_s_setprio(0);

        if (kt >= 2 * qt) {                    // diagonal region mask
            const int qg = qt * 128 + w * 32 + q32;
            #pragma unroll
            for (int r = 0; r < 16; ++r) {
                const int kg = kt * 64 + CROW(r, hi);
                if (kg > qg)      st0[r] = -1e30f;
                if (kg + 32 > qg) st1[r] = -1e30f;
            }
        }

        // ---- row max: pairwise tree (depth 5) + one cross-half exchange
        float tm[16];
        #pragma unroll
        for (int r = 0; r < 16; ++r) tm[r] = fmaxf(st0[r], st1[r]);
        #pragma unroll
        for (int d = 8; d >= 1; d >>= 1)
            #pragma unroll
            for (int r = 0; r < d; ++r) tm[r] = fmaxf(tm[r], tm[r + d]);
        float pm = fmaxf(tm[0], __shfl_xor(tm[0], 32));

        // ---- defer-max rescale (rare)
        if (__any(pm > mloc + DEFER)) {
            const float nm = fmaxf(mloc, pm);
            const float corr = exp2f(mloc - nm);
            mloc = nm;
            #pragma unroll
            for (int r = 0; r < 16; ++r) {
                const float cr = __shfl(corr, CROW(r, hi));
                o0[r] *= cr;
                o1[r] *= cr;
                lv[r] *= cr;
            }
        }

        // ---- exp2 (sum handled by ones-MFMA below)
        #pragma unroll
        for (int r = 0; r < 16; ++r) {
            st0[r] = exp2f(st0[r] - mloc);
            st1[r] = exp2f(st1[r] - mloc);
        }

        // ---- P -> PV A-frags (16 cvt_pk + 8 permlane32_swap, no LDS)
        short8 pa0 = mk(st0[0], st0[1], st0[2],  st0[3],  st0[4],  st0[5],  st0[6],  st0[7]);
        short8 pa1 = mk(st0[8], st0[9], st0[10], st0[11], st0[12], st0[13], st0[14], st0[15]);
        short8 pa2 = mk(st1[0], st1[1], st1[2],  st1[3],  st1[4],  st1[5],  st1[6],  st1[7]);
        short8 pa3 = mk(st1[8], st1[9], st1[10], st1[11], st1[12], st1[13], st1[14], st1[15]);

        // ---- O^T += P V ; lv += P 1   (B = V[k][d] read from Vs = V^T[d][k])
        __builtin_amdgcn_s_setprio(1);
        const int vd0 = q32, vd1 = 32 + q32;
        #pragma unroll
        for (int ks = 0; ks < 4; ++ks) {
            short8 paf = (ks == 0) ? pa0 : (ks == 1) ? pa1 : (ks == 2) ? pa2 : pa3;
            const int c = 16 * ks + hi * 8;
            short8 vb0 = *(const short8*)&Vs[cur][vd0 * 64 + SWC(vd0, c)];
            short8 vb1 = *(const short8*)&Vs[cur][vd1 * 64 + SWC(vd1, c)];
            o0 = __builtin_amdgcn_mfma_f32_32x32x16_bf16(paf, vb0, o0, 0, 0, 0);
            o1 = __builtin_amdgcn_mfma_f32_32x32x16_bf16(paf, vb1, o1, 0, 0, 0);
            lv = __builtin_amdgcn_mfma_f32_32x32x16_bf16(paf, ones, lv, 0, 0, 0);
        }
        __builtin_amdgcn_s_setprio(0);
    }

    if (direct) {
        #pragma unroll
        for (int r = 0; r < 16; ++r) {
            const float inv = 1.f / lv[r];       // row-sum already in o-row layout
            const int t = qt * 128 + w * 32 + CROW(r, hi);
            unsigned short* op = &O[(((size_t)(b * T_ + t)) * 16 + h) * 64 + q32];
            op[0]  = f2bf(o0[r] * inv);
            op[32] = f2bf(o1[r] * inv);
        }
    } else {
        const int p = ((bh << 3) + (qt - 8)) * 2 + ck;
        if (l < 32) PM[p * 128 + w * 32 + l] = mloc;
        if (q32 == 0) {                          // lanes 0 and 32 cover all rows
            #pragma unroll
            for (int r = 0; r < 16; ++r)
                PLp[p * 128 + w * 32 + CROW(r, hi)] = lv[r];
        }
        #pragma unroll
        for (int r = 0; r < 16; ++r) {
            const int row = w * 32 + CROW(r, hi);
            unsigned short* pp = &PACC[((size_t)p * 128 + row) * 64 + q32];
            pp[0]  = f2bf(o0[r]);
            pp[32] = f2bf(o1[r]);
        }
    }
}

// ---------------------------------------------------------------------------
// Combine two split-K partials per (b,h,long-qt).  256 blocks x 256 threads.
// ---------------------------------------------------------------------------
__global__ __launch_bounds__(256) void combine_attn(
        const float* __restrict__ PM, const float* __restrict__ PLp,
        const unsigned short* __restrict__ PACC,
        unsigned short* __restrict__ O) {
    const int cid = blockIdx.x;
    const int bh = cid & 31, qt = 8 + (cid >> 5);
    const int h = bh & 15, b = bh >> 4;
    const int tid = threadIdx.x;
    const int row = tid >> 1, cg = (tid & 1) * 32;
    const int p0 = ((bh << 3) + (qt - 8)) * 2, p1 = p0 + 1;

    float mA = PM[p0 * 128 + row], mB = PM[p1 * 128 + row];
    float lA = PLp[p0 * 128 + row], lB = PLp[p1 * 128 + row];
    float M = fmaxf(mA, mB);
    float wA = exp2f(mA - M), wB = exp2f(mB - M);
    float inv = 1.f / (lA * wA + lB * wB);
    wA *= inv; wB *= inv;

    const unsigned short* a = &PACC[((size_t)p0 * 128 + row) * 64 + cg];
    const unsigned short* c = &PACC[((size_t)p1 * 128 + row) * 64 + cg];
    int t = qt * 128 + row;
    unsigned short* op = &O[(((size_t)(b * T_ + t)) * 16 + h) * 64 + cg];
    #pragma unroll
    for (int j = 0; j < 4; ++j) {
        short8 va = *(const short8*)(a + j * 8);
        short8 vb = *(const short8*)(c + j * 8);
        short8 o;
        #pragma unroll
        for (int i = 0; i < 8; ++i)
            o[i] = f2bf(bf2f((unsigned short)va[i]) * wA +
                        bf2f((unsigned short)vb[i]) * wB);
        *(short8*)(op + j * 8) = o;
    }
}

// ---------------------------------------------------------------------------
extern "C" void kernel_launch(void* const* d_in, const int* in_sizes, int n_in,
                              void* d_out, int out_size, void* d_ws, size_t ws_size,
                              hipStream_t stream) {
    const float* x  = (const float*)d_in[0];
    const float* rc = (const float*)d_in[1];
    const float* rs = (const float*)d_in[2];
    const float* Wq = (const float*)d_in[4];
    const float* Wk = (const float*)d_in[5];
    const float* Wv = (const float*)d_in[6];
    const float* Wo = (const float*)d_in[7];
    float* out = (float*)d_out;

    unsigned short* ws = (unsigned short*)d_ws;
    unsigned short* xb  = ws;                        // 4M shorts (dead after QKV)
    unsigned short* Wt  = ws + 4194304;              // 1.5M (dead after QKV)
    unsigned short* Wot = ws + 5767168;              // 1M
    unsigned short* Qbf = ws + 6815744;              // 4M
    unsigned short* Kbf = ws + 11010048;             // 1M
    unsigned short* Vtb = ws + 12058624;             // 1M
    unsigned short* Ob  = ws + 13107200;             // 4M

    // split-K partials reuse the dead xb/Wt region
    float* PM            = (float*)d_ws;                         // [512][128] f32
    float* PLp           = PM + 512 * 128;                       // [512][128] f32
    unsigned short* PACC = (unsigned short*)(PLp + 512 * 128);   // [512][128][64] bf16

    dim3 blk(256);
    prep_fused<<<dim3(2688), blk, 0, stream>>>(x, Wq, Wk, Wv, Wo, xb, Wt, Wot);

    gemm_qkv<<<dim3(12, 32), blk, 0, stream>>>(xb, Wt, Qbf, Kbf, Vtb, rc, rs);

    attn_mfma<<<dim3(768), blk, 0, stream>>>(Qbf, Kbf, Vtb, Ob, PM, PLp, PACC);
    combine_attn<<<dim3(256), blk, 0, stream>>>(PM, PLp, PACC, Ob);

    gemm_o<<<dim3(16, 32), blk, 0, stream>>>(Ob, Wot, out, 4096, 1024, 1024);
}

// Round 17
// 107.279 us; speedup vs baseline: 1.2954x; 1.0592x over previous
//
#include <hip/hip_runtime.h>

typedef __attribute__((ext_vector_type(8))) short short8;
typedef __attribute__((ext_vector_type(4))) short short4v;
typedef __attribute__((ext_vector_type(4))) float f32x4;
typedef __attribute__((ext_vector_type(16))) float f32x16;
typedef __attribute__((ext_vector_type(2))) unsigned uint2v;
typedef __attribute__((ext_vector_type(4))) unsigned uint4v;

#define T_ 2048
#define H_ 16
#define KVH_ 4
#define QSCALE 0.18033688011112042f   // 0.125 * log2(e): softmax in base-2 domain
#define DEFER 8.0f                    // T13 defer-max threshold (log2 domain)
#define SWC(row, col) ((col) ^ (((row) & 7) << 3))
#define CROW(r, hi) (((r) & 3) + 8 * ((r) >> 2) + 4 * (hi))

__device__ inline unsigned short f2bf(float f) {
    unsigned u = __builtin_bit_cast(unsigned, f);
    u += 0x7fff + ((u >> 16) & 1);
    return (unsigned short)(u >> 16);
}
__device__ inline float bf2f(unsigned short v) {
    unsigned u = ((unsigned)v) << 16;
    return __builtin_bit_cast(float, u);
}
__device__ inline unsigned pk2(float lo, float hi) {
    unsigned r;
    asm("v_cvt_pk_bf16_f32 %0, %1, %2" : "=v"(r) : "v"(lo), "v"(hi));
    return r;
}

__device__ inline void gl_lds16(const unsigned short* g, unsigned short* lds) {
    __builtin_amdgcn_global_load_lds(
        (const __attribute__((address_space(1))) unsigned int*)g,
        (__attribute__((address_space(3))) unsigned int*)lds, 16, 0, 0);
}

// ---------------------------------------------------------------------------
// Fused prep: bid <2048: x f32->bf16 cast (8/thread);
//             2048..2303: Wq transpose; 2304..2367: Wk; 2368..2431: Wv;
//             2432..2687: Wo.   W [K][N] f32 -> out [rowoff+N][K] bf16.
// ---------------------------------------------------------------------------
__device__ void tr_tile(const float* __restrict__ W, unsigned short* __restrict__ out,
                        int K, int N, int rowoff, int bx, int by, int tid,
                        unsigned short (*ts)[66]) {
    #pragma unroll
    for (int s = 0; s < 16; ++s) {
        int idx = tid + s * 256;
        int kl = idx >> 6, nl = idx & 63;
        ts[kl][nl] = f2bf(W[(size_t)(by * 64 + kl) * N + bx * 64 + nl]);
    }
    __syncthreads();
    #pragma unroll
    for (int s = 0; s < 16; ++s) {
        int idx = tid + s * 256;
        int nl = idx >> 6, kl = idx & 63;
        out[(size_t)(rowoff + bx * 64 + nl) * K + by * 64 + kl] = ts[kl][nl];
    }
}

__global__ __launch_bounds__(256) void prep_fused(
        const float* __restrict__ x,
        const float* __restrict__ Wq, const float* __restrict__ Wk,
        const float* __restrict__ Wv, const float* __restrict__ Wo,
        unsigned short* __restrict__ xb, unsigned short* __restrict__ Wt,
        unsigned short* __restrict__ Wot) {
    __shared__ unsigned short ts[64][66];
    const int bid = blockIdx.x, tid = threadIdx.x;
    if (bid < 2048) {
        int i = bid * 256 + tid;
        float4 v0 = ((const float4*)x)[i * 2];
        float4 v1 = ((const float4*)x)[i * 2 + 1];
        short8 o;
        o[0] = f2bf(v0.x); o[1] = f2bf(v0.y); o[2] = f2bf(v0.z); o[3] = f2bf(v0.w);
        o[4] = f2bf(v1.x); o[5] = f2bf(v1.y); o[6] = f2bf(v1.z); o[7] = f2bf(v1.w);
        ((short8*)xb)[i] = o;
    } else if (bid < 2304) {
        int t = bid - 2048;
        tr_tile(Wq, Wt, 1024, 1024, 0, t & 15, t >> 4, tid, ts);
    } else if (bid < 2368) {
        int t = bid - 2304;
        tr_tile(Wk, Wt, 1024, 256, 1024, t & 3, t >> 2, tid, ts);
    } else if (bid < 2432) {
        int t = bid - 2368;
        tr_tile(Wv, Wt, 1024, 256, 1280, t & 3, t >> 2, tid, ts);
    } else {
        int t = bid - 2432;
        tr_tile(Wo, Wot, 1024, 1024, 0, t & 15, t >> 4, tid, ts);
    }
}

// ---------------------------------------------------------------------------
// QKV GEMM: 128x128 tile, BK=64 (half the barriers of BK=32), gl_lds16
// staging with pre-swizzled global source (linear LDS dest, SWC on read ->
// 2-way conflicts = free).  Fused RoPE/K/V epilogue per 64-col group.
// ---------------------------------------------------------------------------
__global__ __launch_bounds__(256) void gemm_qkv(
        const unsigned short* __restrict__ A,
        const unsigned short* __restrict__ Bt,
        unsigned short* __restrict__ Cq, unsigned short* __restrict__ Ck,
        unsigned short* __restrict__ Cvt,
        const float* __restrict__ rc, const float* __restrict__ rs) {
    const int K = 1024;
    __shared__ __align__(16) unsigned short As[128 * 64];
    __shared__ __align__(16) unsigned short Bs[128 * 64];
    const int tid = threadIdx.x;
    const int w = tid >> 6, l = tid & 63, lk = l & 15, lg = l >> 4;
    const int wr = w >> 1, wc = w & 1;
    const int bx = blockIdx.x, by = blockIdx.y;

    const unsigned short* Arow = A + (size_t)by * 128 * K;
    const unsigned short* Brow = Bt + (size_t)bx * 128 * K;

    f32x4 acc[4][4];
    #pragma unroll
    for (int m = 0; m < 4; ++m)
        #pragma unroll
        for (int n = 0; n < 4; ++n) acc[m][n] = (f32x4){0, 0, 0, 0};

    for (int k0 = 0; k0 < K; k0 += 64) {
        #pragma unroll
        for (int p = 0; p < 4; ++p) {
            int cb = p * 256 + w * 64;          // wave-uniform chunk base
            int c = cb + l;
            int row = c >> 3;
            int ko = ((c & 7) ^ (row & 7)) * 8; // pre-swizzled source (m173)
            gl_lds16(Arow + (size_t)row * K + k0 + ko, As + (size_t)cb * 8);
            gl_lds16(Brow + (size_t)row * K + k0 + ko, Bs + (size_t)cb * 8);
        }
        __syncthreads();
        #pragma unroll
        for (int kk = 0; kk < 2; ++kk) {
            short8 aF[4], bF[4];
            #pragma unroll
            for (int m = 0; m < 4; ++m) {
                const int row = wr * 64 + m * 16 + lk;
                aF[m] = *(const short8*)&As[row * 64 + SWC(row, kk * 32 + lg * 8)];
            }
            #pragma unroll
            for (int n = 0; n < 4; ++n) {
                const int row = wc * 64 + n * 16 + lk;
                bF[n] = *(const short8*)&Bs[row * 64 + SWC(row, kk * 32 + lg * 8)];
            }
            #pragma unroll
            for (int m = 0; m < 4; ++m)
                #pragma unroll
                for (int n = 0; n < 4; ++n)
                    acc[m][n] = __builtin_amdgcn_mfma_f32_16x16x32_bf16(
                        aF[m], bF[n], acc[m][n], 0, 0, 0);
        }
        __syncthreads();
    }

    const int rowbase = by * 128 + wr * 64;
    const int colgrp = bx * 2 + wc;
    if (colgrp < 16) {                  // ---- Q: RoPE * QSCALE
        const int h = colgrp;
        #pragma unroll
        for (int m = 0; m < 4; ++m)
            #pragma unroll
            for (int r = 0; r < 4; ++r) {
                int trow = rowbase + m * 16 + lg * 4 + r;
                int b = trow >> 11, t = trow & (T_ - 1);
                size_t ob = (((size_t)(b * 16 + h)) * T_ + t) * 64;
                #pragma unroll
                for (int n = 0; n < 2; ++n) {
                    int d = n * 16 + lk;
                    float cc = rc[t * 32 + d], ss = rs[t * 32 + d];
                    float x1 = acc[m][n][r], x2 = acc[m][n + 2][r];
                    Cq[ob + d]      = f2bf((x1 * cc - x2 * ss) * QSCALE);
                    Cq[ob + d + 32] = f2bf((x2 * cc + x1 * ss) * QSCALE);
                }
            }
    } else if (colgrp < 20) {           // ---- K: RoPE
        const int kvh = colgrp - 16;
        #pragma unroll
        for (int m = 0; m < 4; ++m)
            #pragma unroll
            for (int r = 0; r < 4; ++r) {
                int trow = rowbase + m * 16 + lg * 4 + r;
                int b = trow >> 11, t = trow & (T_ - 1);
                size_t ob = (((size_t)(b * 4 + kvh)) * T_ + t) * 64;
                #pragma unroll
                for (int n = 0; n < 2; ++n) {
                    int d = n * 16 + lk;
                    float cc = rc[t * 32 + d], ss = rs[t * 32 + d];
                    float x1 = acc[m][n][r], x2 = acc[m][n + 2][r];
                    Ck[ob + d]      = f2bf(x1 * cc - x2 * ss);
                    Ck[ob + d + 32] = f2bf(x2 * cc + x1 * ss);
                }
            }
    } else {                            // ---- V -> [B][4][64][T]
        const int kvh = colgrp - 20;
        #pragma unroll
        for (int m = 0; m < 4; ++m) {
            int trow0 = rowbase + m * 16 + lg * 4;
            int b = trow0 >> 11, t0 = trow0 & (T_ - 1);
            #pragma unroll
            for (int n = 0; n < 4; ++n) {
                int d = n * 16 + lk;
                short4v pk;
                #pragma unroll
                for (int r = 0; r < 4; ++r) pk[r] = f2bf(acc[m][n][r]);
                *(short4v*)(Cvt + (((size_t)(b * 4 + kvh)) * 64 + d) * T_ + t0) = pk;
            }
        }
    }
}

// ---------------------------------------------------------------------------
// O-projection GEMM: 128x64 tile, BK=64, swizzled staging.  C = f32 [M][N].
// ---------------------------------------------------------------------------
__global__ __launch_bounds__(256) void gemm_o(
        const unsigned short* __restrict__ A,
        const unsigned short* __restrict__ Bt,
        float* __restrict__ C, int M, int N, int K) {
    __shared__ __align__(16) unsigned short As[128 * 64];
    __shared__ __align__(16) unsigned short Bs[64 * 64];
    const int tid = threadIdx.x;
    const int w = tid >> 6, l = tid & 63, lk = l & 15, lg = l >> 4;
    const int bx = blockIdx.x, by = blockIdx.y;

    const unsigned short* Arow = A + (size_t)by * 128 * K;
    const unsigned short* Brow = Bt + (size_t)bx * 64 * K;

    f32x4 acc[2][4];
    #pragma unroll
    for (int m = 0; m < 2; ++m)
        #pragma unroll
        for (int n = 0; n < 4; ++n) acc[m][n] = (f32x4){0, 0, 0, 0};

    for (int k0 = 0; k0 < K; k0 += 64) {
        #pragma unroll
        for (int p = 0; p < 4; ++p) {
            int cb = p * 256 + w * 64;
            int c = cb + l;
            int row = c >> 3;
            int ko = ((c & 7) ^ (row & 7)) * 8;
            gl_lds16(Arow + (size_t)row * K + k0 + ko, As + (size_t)cb * 8);
        }
        #pragma unroll
        for (int p = 0; p < 2; ++p) {
            int cb = p * 256 + w * 64;
            int c = cb + l;
            int row = c >> 3;
            int ko = ((c & 7) ^ (row & 7)) * 8;
            gl_lds16(Brow + (size_t)row * K + k0 + ko, Bs + (size_t)cb * 8);
        }
        __syncthreads();
        #pragma unroll
        for (int kk = 0; kk < 2; ++kk) {
            short8 aF[2], bF[4];
            #pragma unroll
            for (int m = 0; m < 2; ++m) {
                const int row = w * 32 + m * 16 + lk;
                aF[m] = *(const short8*)&As[row * 64 + SWC(row, kk * 32 + lg * 8)];
            }
            #pragma unroll
            for (int n = 0; n < 4; ++n) {
                const int row = n * 16 + lk;
                bF[n] = *(const short8*)&Bs[row * 64 + SWC(row, kk * 32 + lg * 8)];
            }
            #pragma unroll
            for (int m = 0; m < 2; ++m)
                #pragma unroll
                for (int n = 0; n < 4; ++n)
                    acc[m][n] = __builtin_amdgcn_mfma_f32_16x16x32_bf16(
                        aF[m], bF[n], acc[m][n], 0, 0, 0);
        }
        __syncthreads();
    }

    const int rowbase = by * 128 + w * 32;
    #pragma unroll
    for (int m = 0; m < 2; ++m)
        #pragma unroll
        for (int r = 0; r < 4; ++r) {
            size_t ro = (size_t)(rowbase + m * 16 + lg * 4 + r) * N + bx * 64 + lk;
            #pragma unroll
            for (int n = 0; n < 4; ++n) C[ro + n * 16] = acc[m][n][r];
        }
}

// ---------------------------------------------------------------------------
// Flash attention v12 (r16, best: ~53us): swapped QK^T (mfma_32x32x16),
// in-register softmax, cvt_pk + permlane32_swap, lsum via ones-MFMA,
// XOR-swizzled LDS staging, tree max-reduce, r10 split-K mapping.
// ---------------------------------------------------------------------------
__global__ __launch_bounds__(256) void attn_mfma(
        const unsigned short* __restrict__ Q,   // [B][16][T][64] (pre-scaled, log2 domain)
        const unsigned short* __restrict__ K,   // [B][4][T][64]
        const unsigned short* __restrict__ Vt,  // [B][4][64][T]
        unsigned short* __restrict__ O,         // [B*T][16][64] bf16
        float* __restrict__ PM, float* __restrict__ PLp,
        unsigned short* __restrict__ PACC) {
    __shared__ __align__(16) unsigned short Ks[2][64 * 64];
    __shared__ __align__(16) unsigned short Vs[2][64 * 64];

    const int bid = blockIdx.x;
    int bh, qt, kt0, ktend, ck;
    bool direct;
    if (bid < 256) {
        bh = bid & 31; qt = 8 + (bid >> 5);
        kt0 = 0; ktend = 16; ck = 0; direct = false;
    } else if (bid < 512) {
        int j = bid - 256;
        bh = j & 31; qt = 7 - (j >> 5);
        kt0 = 0; ktend = 2 * qt + 2; ck = 0; direct = true;
    } else {
        int j = bid - 512;
        bh = j & 31; qt = 15 - (j >> 5);     // r10 mapping (empirical best)
        kt0 = 16; ktend = 2 * qt + 2; ck = 1; direct = false;
    }
    const int nkt = ktend - kt0;
    const int h = bh & 15, b = bh >> 4, kv = h >> 2;
    const int tid = threadIdx.x;
    const int w = tid >> 6, l = tid & 63;
    const int q32 = l & 31, hi = l >> 5;

    const unsigned short* Kb = K + ((size_t)(b * 4 + kv)) * T_ * 64;
    const unsigned short* Vb = Vt + ((size_t)(b * 4 + kv)) * 64 * T_;

    // Q B-frags: lane holds q=l&31, d=16s+hi*8+j
    short8 qf[4];
    {
        const unsigned short* qp =
            Q + (((size_t)(b * 16 + h)) * T_ + qt * 128 + w * 32 + q32) * 64 + hi * 8;
        #pragma unroll
        for (int s = 0; s < 4; ++s) qf[s] = *(const short8*)(qp + 16 * s);
    }

    f32x16 o0, o1, lv;            // O^T halves + row-sum accumulator (ones-MFMA)
    #pragma unroll
    for (int i = 0; i < 16; ++i) { o0[i] = 0.f; o1[i] = 0.f; lv[i] = 0.f; }
    float mloc = -1e38f;

    short8 ones;
    #pragma unroll
    for (int i = 0; i < 8; ++i) ones[i] = (short)0x3F80;   // bf16 1.0

    // staging: linear LDS dest, pre-swizzled global source (m173 pattern)
    const int sr = l >> 3, sg = l & 7;
    auto stage = [&](int buf, int kt) {
        #pragma unroll
        for (int p = 0; p < 2; ++p) {
            const int ch = w * 2 + p;
            const int row = ch * 8 + sr;
            const int gs = (sg ^ sr) * 8;
            gl_lds16(Kb + ((size_t)(kt * 64 + row)) * 64 + gs, &Ks[buf][ch * 512]);
            gl_lds16(Vb + (size_t)row * T_ + kt * 64 + gs,     &Vs[buf][ch * 512]);
        }
    };

    // build PV A-frag word group from 8 P values (post-exp2, q=lane-local)
    auto mk = [&](float e0, float e1, float e2, float e3,
                  float e4, float e5, float e6, float e7) -> short8 {
        unsigned a0 = pk2(e0, e1);
        unsigned b0 = pk2(e4, e5);
        uint2v r02 = __builtin_amdgcn_permlane32_swap(a0, b0, false, false);
        unsigned a1 = pk2(e2, e3);
        unsigned b1 = pk2(e6, e7);
        uint2v r13 = __builtin_amdgcn_permlane32_swap(a1, b1, false, false);
        uint4v u;
        u[0] = r02[0]; u[1] = r13[0]; u[2] = r02[1]; u[3] = r13[1];
        return __builtin_bit_cast(short8, u);
    };

    stage(0, kt0);
    for (int i = 0; i < nkt; ++i) {
        const int kt = kt0 + i;
        const int cur = i & 1;
        __syncthreads();                       // DMA drained: buf[cur] ready
        if (i + 1 < nkt) stage(cur ^ 1, kt0 + i + 1);

        // ---- S^T = K Q  (A=K rows k, B=Q cols q); two 32-k subtiles
        f32x16 st0, st1;
        #pragma unroll
        for (int r = 0; r < 16; ++r) { st0[r] = 0.f; st1[r] = 0.f; }
        __builtin_amdgcn_s_setprio(1);
        #pragma unroll
        for (int s = 0; s < 4; ++s) {
            const int c = 16 * s + hi * 8;
            const int kr0 = q32, kr1 = 32 + q32;
            short8 k0 = *(const short8*)&Ks[cur][kr0 * 64 + SWC(kr0, c)];
            short8 k1 = *(const short8*)&Ks[cur][kr1 * 64 + SWC(kr1, c)];
            st0 = __builtin_amdgcn_mfma_f32_32x32x16_bf16(k0, qf[s], st0, 0, 0, 0);
            st1 = __builtin_amdgcn_mfma_f32_32x32x16_bf16(k1, qf[s], st1, 0, 0, 0);
        }
        __builtin_amdgcn_s_setprio(0);

        if (kt >= 2 * qt) {                    // diagonal region mask
            const int qg = qt * 128 + w * 32 + q32;
            #pragma unroll
            for (int r = 0; r < 16; ++r) {
                const int kg = kt * 64 + CROW(r, hi);
                if (kg > qg)      st0[r] = -1e30f;
                if (kg + 32 > qg) st1[r] = -1e30f;
            }
        }

        // ---- row max: pairwise tree (depth 5) + one cross-half exchange
        float tm[16];
        #pragma unroll
        for (int r = 0; r < 16; ++r) tm[r] = fmaxf(st0[r], st1[r]);
        #pragma unroll
        for (int d = 8; d >= 1; d >>= 1)
            #pragma unroll
            for (int r = 0; r < d; ++r) tm[r] = fmaxf(tm[r], tm[r + d]);
        float pm = fmaxf(tm[0], __shfl_xor(tm[0], 32));

        // ---- defer-max rescale (rare)
        if (__any(pm > mloc + DEFER)) {
            const float nm = fmaxf(mloc, pm);
            const float corr = exp2f(mloc - nm);
            mloc = nm;
            #pragma unroll
            for (int r = 0; r < 16; ++r) {
                const float cr = __shfl(corr, CROW(r, hi));
                o0[r] *= cr;
                o1[r] *= cr;
                lv[r] *= cr;
            }
        }

        // ---- exp2 (sum handled by ones-MFMA below)
        #pragma unroll
        for (int r = 0; r < 16; ++r) {
            st0[r] = exp2f(st0[r] - mloc);
            st1[r] = exp2f(st1[r] - mloc);
        }

        // ---- P -> PV A-frags (16 cvt_pk + 8 permlane32_swap, no LDS)
        short8 pa0 = mk(st0[0], st0[1], st0[2],  st0[3],  st0[4],  st0[5],  st0[6],  st0[7]);
        short8 pa1 = mk(st0[8], st0[9], st0[10], st0[11], st0[12], st0[13], st0[14], st0[15]);
        short8 pa2 = mk(st1[0], st1[1], st1[2],  st1[3],  st1[4],  st1[5],  st1[6],  st1[7]);
        short8 pa3 = mk(st1[8], st1[9], st1[10], st1[11], st1[12], st1[13], st1[14], st1[15]);

        // ---- O^T += P V ; lv += P 1   (B = V[k][d] read from Vs = V^T[d][k])
        __builtin_amdgcn_s_setprio(1);
        const int vd0 = q32, vd1 = 32 + q32;
        #pragma unroll
        for (int ks = 0; ks < 4; ++ks) {
            short8 paf = (ks == 0) ? pa0 : (ks == 1) ? pa1 : (ks == 2) ? pa2 : pa3;
            const int c = 16 * ks + hi * 8;
            short8 vb0 = *(const short8*)&Vs[cur][vd0 * 64 + SWC(vd0, c)];
            short8 vb1 = *(const short8*)&Vs[cur][vd1 * 64 + SWC(vd1, c)];
            o0 = __builtin_amdgcn_mfma_f32_32x32x16_bf16(paf, vb0, o0, 0, 0, 0);
            o1 = __builtin_amdgcn_mfma_f32_32x32x16_bf16(paf, vb1, o1, 0, 0, 0);
            lv = __builtin_amdgcn_mfma_f32_32x32x16_bf16(paf, ones, lv, 0, 0, 0);
        }
        __builtin_amdgcn_s_setprio(0);
    }

    if (direct) {
        #pragma unroll
        for (int r = 0; r < 16; ++r) {
            const float inv = 1.f / lv[r];       // row-sum already in o-row layout
            const int t = qt * 128 + w * 32 + CROW(r, hi);
            unsigned short* op = &O[(((size_t)(b * T_ + t)) * 16 + h) * 64 + q32];
            op[0]  = f2bf(o0[r] * inv);
            op[32] = f2bf(o1[r] * inv);
        }
    } else {
        const int p = ((bh << 3) + (qt - 8)) * 2 + ck;
        if (l < 32) PM[p * 128 + w * 32 + l] = mloc;
        if (q32 == 0) {                          // lanes 0 and 32 cover all rows
            #pragma unroll
            for (int r = 0; r < 16; ++r)
                PLp[p * 128 + w * 32 + CROW(r, hi)] = lv[r];
        }
        #pragma unroll
        for (int r = 0; r < 16; ++r) {
            const int row = w * 32 + CROW(r, hi);
            unsigned short* pp = &PACC[((size_t)p * 128 + row) * 64 + q32];
            pp[0]  = f2bf(o0[r]);
            pp[32] = f2bf(o1[r]);
        }
    }
}

// ---------------------------------------------------------------------------
// Combine two split-K partials per (b,h,long-qt).  256 blocks x 256 threads.
// ---------------------------------------------------------------------------
__global__ __launch_bounds__(256) void combine_attn(
        const float* __restrict__ PM, const float* __restrict__ PLp,
        const unsigned short* __restrict__ PACC,
        unsigned short* __restrict__ O) {
    const int cid = blockIdx.x;
    const int bh = cid & 31, qt = 8 + (cid >> 5);
    const int h = bh & 15, b = bh >> 4;
    const int tid = threadIdx.x;
    const int row = tid >> 1, cg = (tid & 1) * 32;
    const int p0 = ((bh << 3) + (qt - 8)) * 2, p1 = p0 + 1;

    float mA = PM[p0 * 128 + row], mB = PM[p1 * 128 + row];
    float lA = PLp[p0 * 128 + row], lB = PLp[p1 * 128 + row];
    float M = fmaxf(mA, mB);
    float wA = exp2f(mA - M), wB = exp2f(mB - M);
    float inv = 1.f / (lA * wA + lB * wB);
    wA *= inv; wB *= inv;

    const unsigned short* a = &PACC[((size_t)p0 * 128 + row) * 64 + cg];
    const unsigned short* c = &PACC[((size_t)p1 * 128 + row) * 64 + cg];
    int t = qt * 128 + row;
    unsigned short* op = &O[(((size_t)(b * T_ + t)) * 16 + h) * 64 + cg];
    #pragma unroll
    for (int j = 0; j < 4; ++j) {
        short8 va = *(const short8*)(a + j * 8);
        short8 vb = *(const short8*)(c + j * 8);
        short8 o;
        #pragma unroll
        for (int i = 0; i < 8; ++i)
            o[i] = f2bf(bf2f((unsigned short)va[i]) * wA +
                        bf2f((unsigned short)vb[i]) * wB);
        *(short8*)(op + j * 8) = o;
    }
}

// ---------------------------------------------------------------------------
extern "C" void kernel_launch(void* const* d_in, const int* in_sizes, int n_in,
                              void* d_out, int out_size, void* d_ws, size_t ws_size,
                              hipStream_t stream) {
    const float* x  = (const float*)d_in[0];
    const float* rc = (const float*)d_in[1];
    const float* rs = (const float*)d_in[2];
    const float* Wq = (const float*)d_in[4];
    const float* Wk = (const float*)d_in[5];
    const float* Wv = (const float*)d_in[6];
    const float* Wo = (const float*)d_in[7];
    float* out = (float*)d_out;

    unsigned short* ws = (unsigned short*)d_ws;
    unsigned short* xb  = ws;                        // 4M shorts (dead after QKV)
    unsigned short* Wt  = ws + 4194304;              // 1.5M (dead after QKV)
    unsigned short* Wot = ws + 5767168;              // 1M
    unsigned short* Qbf = ws + 6815744;              // 4M
    unsigned short* Kbf = ws + 11010048;             // 1M
    unsigned short* Vtb = ws + 12058624;             // 1M
    unsigned short* Ob  = ws + 13107200;             // 4M

    // split-K partials reuse the dead xb/Wt region
    float* PM            = (float*)d_ws;                         // [512][128] f32
    float* PLp           = PM + 512 * 128;                       // [512][128] f32
    unsigned short* PACC = (unsigned short*)(PLp + 512 * 128);   // [512][128][64] bf16

    dim3 blk(256);
    prep_fused<<<dim3(2688), blk, 0, stream>>>(x, Wq, Wk, Wv, Wo, xb, Wt, Wot);

    gemm_qkv<<<dim3(12, 32), blk, 0, stream>>>(xb, Wt, Qbf, Kbf, Vtb, rc, rs);

    attn_mfma<<<dim3(768), blk, 0, stream>>>(Qbf, Kbf, Vtb, Ob, PM, PLp, PACC);
    combine_attn<<<dim3(256), blk, 0, stream>>>(PM, PLp, PACC, Ob);

    gemm_o<<<dim3(16, 32), blk, 0, stream>>>(Ob, Wot, out, 4096, 1024, 1024);
}

// Round 18
// 104.979 us; speedup vs baseline: 1.3238x; 1.0219x over previous
//
#include <hip/hip_runtime.h>

typedef __attribute__((ext_vector_type(8))) short short8;
typedef __attribute__((ext_vector_type(4))) short short4v;
typedef __attribute__((ext_vector_type(4))) float f32x4;
typedef __attribute__((ext_vector_type(16))) float f32x16;
typedef __attribute__((ext_vector_type(2))) unsigned uint2v;
typedef __attribute__((ext_vector_type(4))) unsigned uint4v;

#define T_ 2048
#define H_ 16
#define KVH_ 4
#define QSCALE 0.18033688011112042f   // 0.125 * log2(e): softmax in base-2 domain
#define DEFER 8.0f                    // T13 defer-max threshold (log2 domain)
#define SWC(row, col) ((col) ^ (((row) & 7) << 3))
#define CROW(r, hi) (((r) & 3) + 8 * ((r) >> 2) + 4 * (hi))

__device__ inline unsigned short f2bf(float f) {
    unsigned u = __builtin_bit_cast(unsigned, f);
    u += 0x7fff + ((u >> 16) & 1);
    return (unsigned short)(u >> 16);
}
__device__ inline float bf2f(unsigned short v) {
    unsigned u = ((unsigned)v) << 16;
    return __builtin_bit_cast(float, u);
}
__device__ inline unsigned pk2(float lo, float hi) {
    unsigned r;
    asm("v_cvt_pk_bf16_f32 %0, %1, %2" : "=v"(r) : "v"(lo), "v"(hi));
    return r;
}

__device__ inline void gl_lds16(const unsigned short* g, unsigned short* lds) {
    __builtin_amdgcn_global_load_lds(
        (const __attribute__((address_space(1))) unsigned int*)g,
        (__attribute__((address_space(3))) unsigned int*)lds, 16, 0, 0);
}

// ---------------------------------------------------------------------------
// Fused prep: bid <2048: x f32->bf16 cast (8/thread);
//             2048..2303: Wq transpose; 2304..2367: Wk; 2368..2431: Wv;
//             2432..2687: Wo.   W [K][N] f32 -> out [rowoff+N][K] bf16.
// ---------------------------------------------------------------------------
__device__ void tr_tile(const float* __restrict__ W, unsigned short* __restrict__ out,
                        int K, int N, int rowoff, int bx, int by, int tid,
                        unsigned short (*ts)[66]) {
    #pragma unroll
    for (int s = 0; s < 16; ++s) {
        int idx = tid + s * 256;
        int kl = idx >> 6, nl = idx & 63;
        ts[kl][nl] = f2bf(W[(size_t)(by * 64 + kl) * N + bx * 64 + nl]);
    }
    __syncthreads();
    #pragma unroll
    for (int s = 0; s < 16; ++s) {
        int idx = tid + s * 256;
        int nl = idx >> 6, kl = idx & 63;
        out[(size_t)(rowoff + bx * 64 + nl) * K + by * 64 + kl] = ts[kl][nl];
    }
}

__global__ __launch_bounds__(256) void prep_fused(
        const float* __restrict__ x,
        const float* __restrict__ Wq, const float* __restrict__ Wk,
        const float* __restrict__ Wv, const float* __restrict__ Wo,
        unsigned short* __restrict__ xb, unsigned short* __restrict__ Wt,
        unsigned short* __restrict__ Wot) {
    __shared__ unsigned short ts[64][66];
    const int bid = blockIdx.x, tid = threadIdx.x;
    if (bid < 2048) {
        int i = bid * 256 + tid;
        float4 v0 = ((const float4*)x)[i * 2];
        float4 v1 = ((const float4*)x)[i * 2 + 1];
        short8 o;
        o[0] = f2bf(v0.x); o[1] = f2bf(v0.y); o[2] = f2bf(v0.z); o[3] = f2bf(v0.w);
        o[4] = f2bf(v1.x); o[5] = f2bf(v1.y); o[6] = f2bf(v1.z); o[7] = f2bf(v1.w);
        ((short8*)xb)[i] = o;
    } else if (bid < 2304) {
        int t = bid - 2048;
        tr_tile(Wq, Wt, 1024, 1024, 0, t & 15, t >> 4, tid, ts);
    } else if (bid < 2368) {
        int t = bid - 2304;
        tr_tile(Wk, Wt, 1024, 256, 1024, t & 3, t >> 2, tid, ts);
    } else if (bid < 2432) {
        int t = bid - 2368;
        tr_tile(Wv, Wt, 1024, 256, 1280, t & 3, t >> 2, tid, ts);
    } else {
        int t = bid - 2432;
        tr_tile(Wo, Wot, 1024, 1024, 0, t & 15, t >> 4, tid, ts);
    }
}

// ---------------------------------------------------------------------------
// QKV GEMM: 64x128 tile (grid 12x64 = 768 = exactly 3 blocks/CU), BK=64,
// swizzled gl_lds16 staging. Waves 2x2: each wave 32 rows x 64 cols (one
// full head-column group -> RoPE pairing unchanged). Fused epilogue.
// ---------------------------------------------------------------------------
__global__ __launch_bounds__(256) void gemm_qkv(
        const unsigned short* __restrict__ A,
        const unsigned short* __restrict__ Bt,
        unsigned short* __restrict__ Cq, unsigned short* __restrict__ Ck,
        unsigned short* __restrict__ Cvt,
        const float* __restrict__ rc, const float* __restrict__ rs) {
    const int K = 1024;
    __shared__ __align__(16) unsigned short As[64 * 64];
    __shared__ __align__(16) unsigned short Bs[128 * 64];
    const int tid = threadIdx.x;
    const int w = tid >> 6, l = tid & 63, lk = l & 15, lg = l >> 4;
    const int wr = w >> 1, wc = w & 1;
    const int bx = blockIdx.x, by = blockIdx.y;

    const unsigned short* Arow = A + (size_t)by * 64 * K;
    const unsigned short* Brow = Bt + (size_t)bx * 128 * K;

    f32x4 acc[2][4];
    #pragma unroll
    for (int m = 0; m < 2; ++m)
        #pragma unroll
        for (int n = 0; n < 4; ++n) acc[m][n] = (f32x4){0, 0, 0, 0};

    for (int k0 = 0; k0 < K; k0 += 64) {
        #pragma unroll
        for (int p = 0; p < 2; ++p) {          // A: 64 rows = 512 chunks
            int cb = p * 256 + w * 64;
            int c = cb + l;
            int row = c >> 3;
            int ko = ((c & 7) ^ (row & 7)) * 8;
            gl_lds16(Arow + (size_t)row * K + k0 + ko, As + (size_t)cb * 8);
        }
        #pragma unroll
        for (int p = 0; p < 4; ++p) {          // B: 128 rows = 1024 chunks
            int cb = p * 256 + w * 64;
            int c = cb + l;
            int row = c >> 3;
            int ko = ((c & 7) ^ (row & 7)) * 8;
            gl_lds16(Brow + (size_t)row * K + k0 + ko, Bs + (size_t)cb * 8);
        }
        __syncthreads();
        #pragma unroll
        for (int kk = 0; kk < 2; ++kk) {
            short8 aF[2], bF[4];
            #pragma unroll
            for (int m = 0; m < 2; ++m) {
                const int row = wr * 32 + m * 16 + lk;
                aF[m] = *(const short8*)&As[row * 64 + SWC(row, kk * 32 + lg * 8)];
            }
            #pragma unroll
            for (int n = 0; n < 4; ++n) {
                const int row = wc * 64 + n * 16 + lk;
                bF[n] = *(const short8*)&Bs[row * 64 + SWC(row, kk * 32 + lg * 8)];
            }
            #pragma unroll
            for (int m = 0; m < 2; ++m)
                #pragma unroll
                for (int n = 0; n < 4; ++n)
                    acc[m][n] = __builtin_amdgcn_mfma_f32_16x16x32_bf16(
                        aF[m], bF[n], acc[m][n], 0, 0, 0);
        }
        __syncthreads();
    }

    const int rowbase = by * 64 + wr * 32;
    const int colgrp = bx * 2 + wc;
    if (colgrp < 16) {                  // ---- Q: RoPE * QSCALE
        const int h = colgrp;
        #pragma unroll
        for (int m = 0; m < 2; ++m)
            #pragma unroll
            for (int r = 0; r < 4; ++r) {
                int trow = rowbase + m * 16 + lg * 4 + r;
                int b = trow >> 11, t = trow & (T_ - 1);
                size_t ob = (((size_t)(b * 16 + h)) * T_ + t) * 64;
                #pragma unroll
                for (int n = 0; n < 2; ++n) {
                    int d = n * 16 + lk;
                    float cc = rc[t * 32 + d], ss = rs[t * 32 + d];
                    float x1 = acc[m][n][r], x2 = acc[m][n + 2][r];
                    Cq[ob + d]      = f2bf((x1 * cc - x2 * ss) * QSCALE);
                    Cq[ob + d + 32] = f2bf((x2 * cc + x1 * ss) * QSCALE);
                }
            }
    } else if (colgrp < 20) {           // ---- K: RoPE
        const int kvh = colgrp - 16;
        #pragma unroll
        for (int m = 0; m < 2; ++m)
            #pragma unroll
            for (int r = 0; r < 4; ++r) {
                int trow = rowbase + m * 16 + lg * 4 + r;
                int b = trow >> 11, t = trow & (T_ - 1);
                size_t ob = (((size_t)(b * 4 + kvh)) * T_ + t) * 64;
                #pragma unroll
                for (int n = 0; n < 2; ++n) {
                    int d = n * 16 + lk;
                    float cc = rc[t * 32 + d], ss = rs[t * 32 + d];
                    float x1 = acc[m][n][r], x2 = acc[m][n + 2][r];
                    Ck[ob + d]      = f2bf(x1 * cc - x2 * ss);
                    Ck[ob + d + 32] = f2bf(x2 * cc + x1 * ss);
                }
            }
    } else {                            // ---- V -> [B][4][64][T]
        const int kvh = colgrp - 20;
        #pragma unroll
        for (int m = 0; m < 2; ++m) {
            int trow0 = rowbase + m * 16 + lg * 4;
            int b = trow0 >> 11, t0 = trow0 & (T_ - 1);
            #pragma unroll
            for (int n = 0; n < 4; ++n) {
                int d = n * 16 + lk;
                short4v pk;
                #pragma unroll
                for (int r = 0; r < 4; ++r) pk[r] = f2bf(acc[m][n][r]);
                *(short4v*)(Cvt + (((size_t)(b * 4 + kvh)) * 64 + d) * T_ + t0) = pk;
            }
        }
    }
}

// ---------------------------------------------------------------------------
// O-projection GEMM: 128x64 tile, BK=64, swizzled staging.  C = f32 [M][N].
// ---------------------------------------------------------------------------
__global__ __launch_bounds__(256) void gemm_o(
        const unsigned short* __restrict__ A,
        const unsigned short* __restrict__ Bt,
        float* __restrict__ C, int M, int N, int K) {
    __shared__ __align__(16) unsigned short As[128 * 64];
    __shared__ __align__(16) unsigned short Bs[64 * 64];
    const int tid = threadIdx.x;
    const int w = tid >> 6, l = tid & 63, lk = l & 15, lg = l >> 4;
    const int bx = blockIdx.x, by = blockIdx.y;

    const unsigned short* Arow = A + (size_t)by * 128 * K;
    const unsigned short* Brow = Bt + (size_t)bx * 64 * K;

    f32x4 acc[2][4];
    #pragma unroll
    for (int m = 0; m < 2; ++m)
        #pragma unroll
        for (int n = 0; n < 4; ++n) acc[m][n] = (f32x4){0, 0, 0, 0};

    for (int k0 = 0; k0 < K; k0 += 64) {
        #pragma unroll
        for (int p = 0; p < 4; ++p) {
            int cb = p * 256 + w * 64;
            int c = cb + l;
            int row = c >> 3;
            int ko = ((c & 7) ^ (row & 7)) * 8;
            gl_lds16(Arow + (size_t)row * K + k0 + ko, As + (size_t)cb * 8);
        }
        #pragma unroll
        for (int p = 0; p < 2; ++p) {
            int cb = p * 256 + w * 64;
            int c = cb + l;
            int row = c >> 3;
            int ko = ((c & 7) ^ (row & 7)) * 8;
            gl_lds16(Brow + (size_t)row * K + k0 + ko, Bs + (size_t)cb * 8);
        }
        __syncthreads();
        #pragma unroll
        for (int kk = 0; kk < 2; ++kk) {
            short8 aF[2], bF[4];
            #pragma unroll
            for (int m = 0; m < 2; ++m) {
                const int row = w * 32 + m * 16 + lk;
                aF[m] = *(const short8*)&As[row * 64 + SWC(row, kk * 32 + lg * 8)];
            }
            #pragma unroll
            for (int n = 0; n < 4; ++n) {
                const int row = n * 16 + lk;
                bF[n] = *(const short8*)&Bs[row * 64 + SWC(row, kk * 32 + lg * 8)];
            }
            #pragma unroll
            for (int m = 0; m < 2; ++m)
                #pragma unroll
                for (int n = 0; n < 4; ++n)
                    acc[m][n] = __builtin_amdgcn_mfma_f32_16x16x32_bf16(
                        aF[m], bF[n], acc[m][n], 0, 0, 0);
        }
        __syncthreads();
    }

    const int rowbase = by * 128 + w * 32;
    #pragma unroll
    for (int m = 0; m < 2; ++m)
        #pragma unroll
        for (int r = 0; r < 4; ++r) {
            size_t ro = (size_t)(rowbase + m * 16 + lg * 4 + r) * N + bx * 64 + lk;
            #pragma unroll
            for (int n = 0; n < 4; ++n) C[ro + n * 16] = acc[m][n][r];
        }
}

// ---------------------------------------------------------------------------
// Flash attention v12 (r16, best: ~53us): swapped QK^T (mfma_32x32x16),
// in-register softmax, cvt_pk + permlane32_swap, lsum via ones-MFMA,
// XOR-swizzled LDS staging, tree max-reduce, r10 split-K mapping.
// ---------------------------------------------------------------------------
__global__ __launch_bounds__(256) void attn_mfma(
        const unsigned short* __restrict__ Q,   // [B][16][T][64] (pre-scaled, log2 domain)
        const unsigned short* __restrict__ K,   // [B][4][T][64]
        const unsigned short* __restrict__ Vt,  // [B][4][64][T]
        unsigned short* __restrict__ O,         // [B*T][16][64] bf16
        float* __restrict__ PM, float* __restrict__ PLp,
        unsigned short* __restrict__ PACC) {
    __shared__ __align__(16) unsigned short Ks[2][64 * 64];
    __shared__ __align__(16) unsigned short Vs[2][64 * 64];

    const int bid = blockIdx.x;
    int bh, qt, kt0, ktend, ck;
    bool direct;
    if (bid < 256) {
        bh = bid & 31; qt = 8 + (bid >> 5);
        kt0 = 0; ktend = 16; ck = 0; direct = false;
    } else if (bid < 512) {
        int j = bid - 256;
        bh = j & 31; qt = 7 - (j >> 5);
        kt0 = 0; ktend = 2 * qt + 2; ck = 0; direct = true;
    } else {
        int j = bid - 512;
        bh = j & 31; qt = 15 - (j >> 5);     // r10 mapping (empirical best)
        kt0 = 16; ktend = 2 * qt + 2; ck = 1; direct = false;
    }
    const int nkt = ktend - kt0;
    const int h = bh & 15, b = bh >> 4, kv = h >> 2;
    const int tid = threadIdx.x;
    const int w = tid >> 6, l = tid & 63;
    const int q32 = l & 31, hi = l >> 5;

    const unsigned short* Kb = K + ((size_t)(b * 4 + kv)) * T_ * 64;
    const unsigned short* Vb = Vt + ((size_t)(b * 4 + kv)) * 64 * T_;

    // Q B-frags: lane holds q=l&31, d=16s+hi*8+j
    short8 qf[4];
    {
        const unsigned short* qp =
            Q + (((size_t)(b * 16 + h)) * T_ + qt * 128 + w * 32 + q32) * 64 + hi * 8;
        #pragma unroll
        for (int s = 0; s < 4; ++s) qf[s] = *(const short8*)(qp + 16 * s);
    }

    f32x16 o0, o1, lv;            // O^T halves + row-sum accumulator (ones-MFMA)
    #pragma unroll
    for (int i = 0; i < 16; ++i) { o0[i] = 0.f; o1[i] = 0.f; lv[i] = 0.f; }
    float mloc = -1e38f;

    short8 ones;
    #pragma unroll
    for (int i = 0; i < 8; ++i) ones[i] = (short)0x3F80;   // bf16 1.0

    // staging: linear LDS dest, pre-swizzled global source (m173 pattern)
    const int sr = l >> 3, sg = l & 7;
    auto stage = [&](int buf, int kt) {
        #pragma unroll
        for (int p = 0; p < 2; ++p) {
            const int ch = w * 2 + p;
            const int row = ch * 8 + sr;
            const int gs = (sg ^ sr) * 8;
            gl_lds16(Kb + ((size_t)(kt * 64 + row)) * 64 + gs, &Ks[buf][ch * 512]);
            gl_lds16(Vb + (size_t)row * T_ + kt * 64 + gs,     &Vs[buf][ch * 512]);
        }
    };

    // build PV A-frag word group from 8 P values (post-exp2, q=lane-local)
    auto mk = [&](float e0, float e1, float e2, float e3,
                  float e4, float e5, float e6, float e7) -> short8 {
        unsigned a0 = pk2(e0, e1);
        unsigned b0 = pk2(e4, e5);
        uint2v r02 = __builtin_amdgcn_permlane32_swap(a0, b0, false, false);
        unsigned a1 = pk2(e2, e3);
        unsigned b1 = pk2(e6, e7);
        uint2v r13 = __builtin_amdgcn_permlane32_swap(a1, b1, false, false);
        uint4v u;
        u[0] = r02[0]; u[1] = r13[0]; u[2] = r02[1]; u[3] = r13[1];
        return __builtin_bit_cast(short8, u);
    };

    stage(0, kt0);
    for (int i = 0; i < nkt; ++i) {
        const int kt = kt0 + i;
        const int cur = i & 1;
        __syncthreads();                       // DMA drained: buf[cur] ready
        if (i + 1 < nkt) stage(cur ^ 1, kt0 + i + 1);

        // ---- S^T = K Q  (A=K rows k, B=Q cols q); two 32-k subtiles
        f32x16 st0, st1;
        #pragma unroll
        for (int r = 0; r < 16; ++r) { st0[r] = 0.f; st1[r] = 0.f; }
        __builtin_amdgcn_s_setprio(1);
        #pragma unroll
        for (int s = 0; s < 4; ++s) {
            const int c = 16 * s + hi * 8;
            const int kr0 = q32, kr1 = 32 + q32;
            short8 k0 = *(const short8*)&Ks[cur][kr0 * 64 + SWC(kr0, c)];
            short8 k1 = *(const short8*)&Ks[cur][kr1 * 64 + SWC(kr1, c)];
            st0 = __builtin_amdgcn_mfma_f32_32x32x16_bf16(k0, qf[s], st0, 0, 0, 0);
            st1 = __builtin_amdgcn_mfma_f32_32x32x16_bf16(k1, qf[s], st1, 0, 0, 0);
        }
        __builtin_amdgcn_s_setprio(0);

        if (kt >= 2 * qt) {                    // diagonal region mask
            const int qg = qt * 128 + w * 32 + q32;
            #pragma unroll
            for (int r = 0; r < 16; ++r) {
                const int kg = kt * 64 + CROW(r, hi);
                if (kg > qg)      st0[r] = -1e30f;
                if (kg + 32 > qg) st1[r] = -1e30f;
            }
        }

        // ---- row max: pairwise tree (depth 5) + one cross-half exchange
        float tm[16];
        #pragma unroll
        for (int r = 0; r < 16; ++r) tm[r] = fmaxf(st0[r], st1[r]);
        #pragma unroll
        for (int d = 8; d >= 1; d >>= 1)
            #pragma unroll
            for (int r = 0; r < d; ++r) tm[r] = fmaxf(tm[r], tm[r + d]);
        float pm = fmaxf(tm[0], __shfl_xor(tm[0], 32));

        // ---- defer-max rescale (rare)
        if (__any(pm > mloc + DEFER)) {
            const float nm = fmaxf(mloc, pm);
            const float corr = exp2f(mloc - nm);
            mloc = nm;
            #pragma unroll
            for (int r = 0; r < 16; ++r) {
                const float cr = __shfl(corr, CROW(r, hi));
                o0[r] *= cr;
                o1[r] *= cr;
                lv[r] *= cr;
            }
        }

        // ---- exp2 (sum handled by ones-MFMA below)
        #pragma unroll
        for (int r = 0; r < 16; ++r) {
            st0[r] = exp2f(st0[r] - mloc);
            st1[r] = exp2f(st1[r] - mloc);
        }

        // ---- P -> PV A-frags (16 cvt_pk + 8 permlane32_swap, no LDS)
        short8 pa0 = mk(st0[0], st0[1], st0[2],  st0[3],  st0[4],  st0[5],  st0[6],  st0[7]);
        short8 pa1 = mk(st0[8], st0[9], st0[10], st0[11], st0[12], st0[13], st0[14], st0[15]);
        short8 pa2 = mk(st1[0], st1[1], st1[2],  st1[3],  st1[4],  st1[5],  st1[6],  st1[7]);
        short8 pa3 = mk(st1[8], st1[9], st1[10], st1[11], st1[12], st1[13], st1[14], st1[15]);

        // ---- O^T += P V ; lv += P 1   (B = V[k][d] read from Vs = V^T[d][k])
        __builtin_amdgcn_s_setprio(1);
        const int vd0 = q32, vd1 = 32 + q32;
        #pragma unroll
        for (int ks = 0; ks < 4; ++ks) {
            short8 paf = (ks == 0) ? pa0 : (ks == 1) ? pa1 : (ks == 2) ? pa2 : pa3;
            const int c = 16 * ks + hi * 8;
            short8 vb0 = *(const short8*)&Vs[cur][vd0 * 64 + SWC(vd0, c)];
            short8 vb1 = *(const short8*)&Vs[cur][vd1 * 64 + SWC(vd1, c)];
            o0 = __builtin_amdgcn_mfma_f32_32x32x16_bf16(paf, vb0, o0, 0, 0, 0);
            o1 = __builtin_amdgcn_mfma_f32_32x32x16_bf16(paf, vb1, o1, 0, 0, 0);
            lv = __builtin_amdgcn_mfma_f32_32x32x16_bf16(paf, ones, lv, 0, 0, 0);
        }
        __builtin_amdgcn_s_setprio(0);
    }

    if (direct) {
        #pragma unroll
        for (int r = 0; r < 16; ++r) {
            const float inv = 1.f / lv[r];       // row-sum already in o-row layout
            const int t = qt * 128 + w * 32 + CROW(r, hi);
            unsigned short* op = &O[(((size_t)(b * T_ + t)) * 16 + h) * 64 + q32];
            op[0]  = f2bf(o0[r] * inv);
            op[32] = f2bf(o1[r] * inv);
        }
    } else {
        const int p = ((bh << 3) + (qt - 8)) * 2 + ck;
        if (l < 32) PM[p * 128 + w * 32 + l] = mloc;
        if (q32 == 0) {                          // lanes 0 and 32 cover all rows
            #pragma unroll
            for (int r = 0; r < 16; ++r)
                PLp[p * 128 + w * 32 + CROW(r, hi)] = lv[r];
        }
        #pragma unroll
        for (int r = 0; r < 16; ++r) {
            const int row = w * 32 + CROW(r, hi);
            unsigned short* pp = &PACC[((size_t)p * 128 + row) * 64 + q32];
            pp[0]  = f2bf(o0[r]);
            pp[32] = f2bf(o1[r]);
        }
    }
}

// ---------------------------------------------------------------------------
// Combine two split-K partials per (b,h,long-qt).  256 blocks x 256 threads.
// ---------------------------------------------------------------------------
__global__ __launch_bounds__(256) void combine_attn(
        const float* __restrict__ PM, const float* __restrict__ PLp,
        const unsigned short* __restrict__ PACC,
        unsigned short* __restrict__ O) {
    const int cid = blockIdx.x;
    const int bh = cid & 31, qt = 8 + (cid >> 5);
    const int h = bh & 15, b = bh >> 4;
    const int tid = threadIdx.x;
    const int row = tid >> 1, cg = (tid & 1) * 32;
    const int p0 = ((bh << 3) + (qt - 8)) * 2, p1 = p0 + 1;

    float mA = PM[p0 * 128 + row], mB = PM[p1 * 128 + row];
    float lA = PLp[p0 * 128 + row], lB = PLp[p1 * 128 + row];
    float M = fmaxf(mA, mB);
    float wA = exp2f(mA - M), wB = exp2f(mB - M);
    float inv = 1.f / (lA * wA + lB * wB);
    wA *= inv; wB *= inv;

    const unsigned short* a = &PACC[((size_t)p0 * 128 + row) * 64 + cg];
    const unsigned short* c = &PACC[((size_t)p1 * 128 + row) * 64 + cg];
    int t = qt * 128 + row;
    unsigned short* op = &O[(((size_t)(b * T_ + t)) * 16 + h) * 64 + cg];
    #pragma unroll
    for (int j = 0; j < 4; ++j) {
        short8 va = *(const short8*)(a + j * 8);
        short8 vb = *(const short8*)(c + j * 8);
        short8 o;
        #pragma unroll
        for (int i = 0; i < 8; ++i)
            o[i] = f2bf(bf2f((unsigned short)va[i]) * wA +
                        bf2f((unsigned short)vb[i]) * wB);
        *(short8*)(op + j * 8) = o;
    }
}

// ---------------------------------------------------------------------------
extern "C" void kernel_launch(void* const* d_in, const int* in_sizes, int n_in,
                              void* d_out, int out_size, void* d_ws, size_t ws_size,
                              hipStream_t stream) {
    const float* x  = (const float*)d_in[0];
    const float* rc = (const float*)d_in[1];
    const float* rs = (const float*)d_in[2];
    const float* Wq = (const float*)d_in[4];
    const float* Wk = (const float*)d_in[5];
    const float* Wv = (const float*)d_in[6];
    const float* Wo = (const float*)d_in[7];
    float* out = (float*)d_out;

    unsigned short* ws = (unsigned short*)d_ws;
    unsigned short* xb  = ws;                        // 4M shorts (dead after QKV)
    unsigned short* Wt  = ws + 4194304;              // 1.5M (dead after QKV)
    unsigned short* Wot = ws + 5767168;              // 1M
    unsigned short* Qbf = ws + 6815744;              // 4M
    unsigned short* Kbf = ws + 11010048;             // 1M
    unsigned short* Vtb = ws + 12058624;             // 1M
    unsigned short* Ob  = ws + 13107200;             // 4M

    // split-K partials reuse the dead xb/Wt region
    float* PM            = (float*)d_ws;                         // [512][128] f32
    float* PLp           = PM + 512 * 128;                       // [512][128] f32
    unsigned short* PACC = (unsigned short*)(PLp + 512 * 128);   // [512][128][64] bf16

    dim3 blk(256);
    prep_fused<<<dim3(2688), blk, 0, stream>>>(x, Wq, Wk, Wv, Wo, xb, Wt, Wot);

    gemm_qkv<<<dim3(12, 64), blk, 0, stream>>>(xb, Wt, Qbf, Kbf, Vtb, rc, rs);

    attn_mfma<<<dim3(768), blk, 0, stream>>>(Qbf, Kbf, Vtb, Ob, PM, PLp, PACC);
    combine_attn<<<dim3(256), blk, 0, stream>>>(PM, PLp, PACC, Ob);

    gemm_o<<<dim3(16, 32), blk, 0, stream>>>(Ob, Wot, out, 4096, 1024, 1024);
}